// Round 5
// baseline (287.593 us; speedup 1.0000x reference)
//
#include <hip/hip_runtime.h>
#include <stdint.h>

// DetectionBaseline: SSD post-process. R5: phase-split for rocprof attribution.
//   prep      : per (b,a) box decode + softmax (m,sum)      [batch-shared, 20x dedup]
//   sort      : per (b,c) key build + register bitonic sort -> u16 rank list in ws
//   chunk_nms : per (b,c) chunked greedy NMS, kill-columns in registers -> kept keys
//   merge     : per b truncated pairwise bitonic merges -> top-200 output
// Tiered ws fallback (mono = R4 kernel, verified absmax 0.0).

#define A_N     1280
#define CF      20
#define NC      21
#define B_N     16
#define TOPK    200
#define THREADS 256
#define SORT_N  2048
#define CH      128

// ws layout (bytes)
#define KEYS_BYTES   (B_N * CF * TOPK * 8)                 // 512000 kept-key lists
#define BOX_OFF      KEYS_BYTES                             // float4 [16*1280] = 327680
#define MS_OFF       (BOX_OFF + B_N * A_N * 16)             // float2 [16*1280] = 163840
#define RANKS_OFF    (MS_OFF + B_N * A_N * 8)               // u16 [320*1280]   = 819200
#define WS_B_BYTES   RANKS_OFF                              // 1003520 (R4-prep tier)
#define WS_A_BYTES   (RANKS_OFF + (size_t)B_N * CF * A_N * 2)  // 1822720 (split tier)

static __device__ __forceinline__ uint64_t pack_key(float sc, uint32_t idx) {
    // softmax scores positive -> float bits monotone. ~bits => ascending key = descending
    // score; low 32 bits = index => ties break toward smaller index (stable argsort / top_k).
    return ((uint64_t)(uint32_t)(~__float_as_uint(sc)) << 32) | (uint64_t)idx;
}

static __device__ __forceinline__ float box_area(const float4 v) {
    return (v.z - v.x) * (v.w - v.y);
}

static __device__ __forceinline__ bool iou_gt(const float4 a, const float aarea,
                                              const float4 b, const float barea) {
    // ref-exact: inter/(area_a+area_b-inter) > 0.45  (exactly symmetric in IEEE)
    const float lx = fmaxf(a.x, b.x);
    const float ly = fmaxf(a.y, b.y);
    const float rx = fminf(a.z, b.z);
    const float ry = fminf(a.w, b.w);
    const float wx = fmaxf(rx - lx, 0.0f);
    const float wy = fmaxf(ry - ly, 0.0f);
    const float inter = wx * wy;
    const float uni   = aarea + barea - inter;
    return inter / uni > 0.45f;
}

static __device__ __forceinline__ float4 decode_box(const float4 lc, const float4 an) {
    const float cx = lc.x * an.z / 10.0f + an.x;
    const float cy = lc.y * an.w / 10.0f + an.y;
    const float w  = expf(lc.z / 5.0f) * an.z;
    const float h  = expf(lc.w / 5.0f) * an.w;
    float4 v;
    v.x = cx - w / 2.0f; v.y = cy - h / 2.0f;
    v.z = cx + w / 2.0f; v.w = cy + h / 2.0f;
    return v;
}

// ---- prep: per (b,a) decoded box + softmax (max, sum) ----
__global__ __launch_bounds__(THREADS)
void prep_kernel(const float* __restrict__ locs,
                 const float* __restrict__ scores,
                 const float* __restrict__ anchors,
                 float4* __restrict__ boxes_ws,
                 float2* __restrict__ ms_ws)
{
    const int g = blockIdx.x * THREADS + threadIdx.x;
    if (g >= B_N * A_N) return;
    const int a = g % A_N;
    boxes_ws[g] = decode_box(((const float4*)locs)[g], ((const float4*)anchors)[a]);
    const float* sp = scores + (size_t)g * NC;
    float m = sp[0];
    #pragma unroll
    for (int k = 1; k < NC; ++k) m = fmaxf(m, sp[k]);
    float sum = 0.0f;
    #pragma unroll
    for (int k = 0; k < NC; ++k) sum += expf(sp[k] - m);
    ms_ws[g] = make_float2(m, sum);
}

// ---- sort: per (b,c) build keys, register bitonic sort, emit u16 rank list ----
__global__ __launch_bounds__(THREADS)
void sort_kernel(const float* __restrict__ scores,
                 const float2* __restrict__ ms_ws,
                 unsigned short* __restrict__ ranks_ws)
{
    __shared__ uint64_t skeys[SORT_N];   // 16 KB

    const int blk = blockIdx.x;
    const int b   = blk / CF;
    const int c   = blk % CF + 1;
    const int t   = threadIdx.x;
    const int l   = t & 63;
    const int w   = t >> 6;

    #pragma unroll
    for (int i = 0; i < A_N / THREADS; ++i) {
        const int a = t + i * THREADS;
        const float2 ms = ms_ws[b * A_N + a];
        const float  sl = scores[((size_t)b * A_N + a) * NC + c];
        const float  sc = expf(sl - ms.x) / ms.y;          // ref-exact softmax value
        skeys[a] = (sc > 0.01f) ? pack_key(sc, (uint32_t)a) : ~0ull;
    }
    for (int i = A_N + t; i < SORT_N; i += THREADS) skeys[i] = ~0ull;
    __syncthreads();

    // register/wave bitonic sort, element e = w*512 + r*64 + l (R4-verified)
    uint64_t k[8];
    #pragma unroll
    for (int r = 0; r < 8; ++r) k[r] = skeys[(w << 9) + (r << 6) + l];

    for (int kk = 2; kk <= SORT_N; kk <<= 1) {
        for (int j = kk >> 1; j; j >>= 1) {
            if (j >= 512) {
                __syncthreads();
                #pragma unroll
                for (int r = 0; r < 8; ++r) skeys[(w << 9) + (r << 6) + l] = k[r];
                __syncthreads();
                #pragma unroll
                for (int r = 0; r < 8; ++r) {
                    const int e = (w << 9) + (r << 6) + l;
                    const uint64_t o = skeys[e ^ j];
                    const bool keep_min = (((e & j) == 0) == ((e & kk) == 0));
                    const uint64_t mn = k[r] < o ? k[r] : o;
                    const uint64_t mx = k[r] < o ? o : k[r];
                    k[r] = keep_min ? mn : mx;
                }
            } else if (j >= 64) {
                const int rb = j >> 6;
                #pragma unroll
                for (int r = 0; r < 8; ++r) {
                    if ((r & rb) == 0) {
                        const int p = r | rb;
                        const int e = (w << 9) + (r << 6) + l;
                        const bool up = ((e & kk) == 0);
                        const uint64_t x = k[r], y = k[p];
                        const uint64_t mn = x < y ? x : y;
                        const uint64_t mx = x < y ? y : x;
                        k[r] = up ? mn : mx;
                        k[p] = up ? mx : mn;
                    }
                }
            } else {
                #pragma unroll
                for (int r = 0; r < 8; ++r) {
                    const uint64_t o = (uint64_t)__shfl_xor((unsigned long long)k[r], j, 64);
                    const int e = (w << 9) + (r << 6) + l;
                    const bool keep_min = (((e & j) == 0) == ((e & kk) == 0));
                    const uint64_t mn = k[r] < o ? k[r] : o;
                    const uint64_t mx = k[r] < o ? o : k[r];
                    k[r] = keep_min ? mn : mx;
                }
            }
        }
    }
    // valid candidates <= 1280, so ranks >= 1280 are all-invalid: store first 1280 only
    unsigned short* const dst = ranks_ws + (size_t)blk * A_N;
    #pragma unroll
    for (int r = 0; r < 8; ++r) {
        const int e = (w << 9) + (r << 6) + l;
        if (e < A_N)
            dst[e] = (k[r] == ~0ull) ? (unsigned short)0xFFFF
                                     : (unsigned short)(k[r] & 0xFFFF);
    }
}

// ---- chunk_nms: greedy NMS over sorted ranks; kill-columns live in wave-0 registers ----
__global__ __launch_bounds__(THREADS)
void chunk_nms_kernel(const float* __restrict__ scores,
                      const float2* __restrict__ ms_ws,
                      const float4* __restrict__ boxes_ws,
                      const unsigned short* __restrict__ ranks_ws,
                      uint64_t* __restrict__ ws_keys)
{
    __shared__ unsigned short sranks[A_N];   // 2.5 KB
    __shared__ float4         schunk[CH];    // 2 KB
    __shared__ uint64_t       scolB[64][2];  // wave-1 column halves (1 KB)
    __shared__ unsigned char  sdead[CH];
    __shared__ float4         swbox[TOPK];   // winner boxes (cross-test)
    __shared__ unsigned short swidx[TOPK];   // winner anchor ids (rank order)
    __shared__ int            sW;

    const int blk = blockIdx.x;
    const int b   = blk / CF;
    const int c   = blk % CF + 1;
    const int t   = threadIdx.x;
    const int l   = t & 63;
    const int w   = t >> 6;

    const unsigned short* const rsrc = ranks_ws + (size_t)blk * A_N;
    for (int i = t; i < A_N; i += THREADS) sranks[i] = rsrc[i];
    if (t == 0) sW = 0;
    __syncthreads();

    int W = 0;
    for (int cb = 0; cb < A_N; cb += CH) {
        if (sranks[cb] == 0xFFFF) break;      // sorted: rest invalid (uniform)

        // phase A: gather chunk boxes
        if (t < CH) {
            const unsigned short rk = sranks[cb + t];
            schunk[t] = (rk != 0xFFFF) ? boxes_ws[(size_t)b * A_N + rk]
                                       : make_float4(-8.f, -8.f, -8.f, -8.f);
        }
        __syncthreads();

        const float4 box_lo = schunk[l];
        const float4 box_hi = schunk[64 + l];

        // phase B: waves 0/1 build kill-columns; waves 2/3 cross-test vs prior winners
        uint64_t c0 = 0, c1 = 0;             // wave 0: bits w in [0,64) of col l / col 64+l
        if (w < 2) {
            const float al = box_area(box_lo);
            const float ah = box_area(box_hi);
            const int wbase = w * 64;        // winner rows this wave covers
            uint64_t m0 = 0, m1 = 0;
            for (int j = 0; j < 64; ++j) {
                const float4 bw = schunk[wbase + j];   // uniform -> LDS broadcast
                const float  aw = box_area(bw);
                if (iou_gt(bw, aw, box_lo, al)) m0 |= (1ull << j);
                if (iou_gt(bw, aw, box_hi, ah)) m1 |= (1ull << j);
            }
            if (w == 1) { scolB[l][0] = m0; scolB[l][1] = m1; }
            else        { c0 = m0; c1 = m1; }
        } else {
            const int     x  = (w == 2) ? l : 64 + l;
            const float4  bxv = (w == 2) ? box_lo : box_hi;
            const float   ax = box_area(bxv);
            const unsigned short rkx = sranks[cb + x];
            int dead = (rkx == 0xFFFF) ? 1 : 0;
            for (int i = 0; i < W && !dead; ++i) {
                const float4 bw = swbox[i];
                if (iou_gt(bw, box_area(bw), bxv, ax)) dead = 1;
            }
            sdead[x] = (unsigned char)dead;
        }
        __syncthreads();

        // phase C: wave 0 resolves chunk in rank order -- no LDS in the dependent chain
        if (w == 0) {
            const uint64_t h0 = scolB[l][0];   // bits w in [64,128) of col l
            const uint64_t h1 = scolB[l][1];   // bits w in [64,128) of col 64+l
            const unsigned short rk0 = sranks[cb + l];
            const unsigned short rk1 = sranks[cb + 64 + l];
            bool a0 = !sdead[l];
            bool a1 = !sdead[64 + l];
            int Wl = W;
            while (true) {
                const unsigned long long b0 = __ballot(a0);
                const unsigned long long b1 = __ballot(a1);
                if (!(b0 | b1)) break;
                const int f = b0 ? (__ffsll(b0) - 1) : (64 + __ffsll(b1) - 1);
                if (f < 64) {
                    if (l == f)      { swidx[Wl] = rk0; swbox[Wl] = box_lo; }
                } else {
                    if (l == f - 64) { swidx[Wl] = rk1; swbox[Wl] = box_hi; }
                }
                uint32_t k0, k1;
                if (f < 64) { k0 = (uint32_t)(c0 >> f) & 1;        k1 = (uint32_t)(c1 >> f) & 1; }
                else        { k0 = (uint32_t)(h0 >> (f - 64)) & 1; k1 = (uint32_t)(h1 >> (f - 64)) & 1; }
                a0 = a0 && !k0;                 // winner self-clears (IoU=1)
                a1 = a1 && !k1;
                if (++Wl >= TOPK) break;        // later winners can't reach output
            }
            if (l == 0) sW = Wl;
        }
        __syncthreads();
        W = sW;
        if (W >= TOPK) break;
    }

    // epilogue: reconstruct keys (bitwise == sort_kernel's) and write kept list
    const uint32_t  base = (uint32_t)(c - 1) * A_N;
    uint64_t* const out  = ws_keys + ((size_t)b * CF + (c - 1)) * TOPK;
    for (int k2 = t; k2 < TOPK; k2 += THREADS) {
        if (k2 < W) {
            const int a = swidx[k2];
            const float2 ms = ms_ws[(size_t)b * A_N + a];
            const float  sc = expf(scores[((size_t)b * A_N + a) * NC + c] - ms.x) / ms.y;
            out[k2] = ((uint64_t)(uint32_t)(~__float_as_uint(sc)) << 32)
                    | (uint64_t)(base + (uint32_t)a);
        } else {
            out[k2] = ~0ull;
        }
    }
}

// ---- mono fallback (R4 kernel, verified) for small ws ----
template <bool PREP>
__global__ __launch_bounds__(THREADS)
void nms_mono(const float* __restrict__ locs,
              const float* __restrict__ scores,
              const float* __restrict__ anchors,
              const float4* __restrict__ boxes_ws,
              const float2* __restrict__ ms_ws,
              uint64_t* __restrict__ ws_keys)
{
    __shared__ uint64_t      skeys[SORT_N];
    __shared__ float4        sbox[A_N];
    __shared__ float4        schunk[CH];
    __shared__ uint64_t      srow[CH][2];
    __shared__ float4        swbox[TOPK];
    __shared__ uint64_t      swkey[TOPK];
    __shared__ unsigned char sdead[CH];
    __shared__ int           sW;

    const int blk = blockIdx.x;
    const int b   = blk / CF;
    const int c   = blk % CF + 1;
    const int t   = threadIdx.x;
    const int l   = t & 63;
    const int w   = t >> 6;

    #pragma unroll
    for (int i = 0; i < A_N / THREADS; ++i) {
        const int a = t + i * THREADS;
        float4 v; float m, sum;
        if (PREP) {
            v = boxes_ws[b * A_N + a];
            const float2 ms = ms_ws[b * A_N + a];
            m = ms.x; sum = ms.y;
        } else {
            v = decode_box(((const float4*)locs)[(size_t)b * A_N + a],
                           ((const float4*)anchors)[a]);
            const float* sp = scores + ((size_t)b * A_N + a) * NC;
            m = sp[0];
            #pragma unroll
            for (int k = 1; k < NC; ++k) m = fmaxf(m, sp[k]);
            sum = 0.0f;
            #pragma unroll
            for (int k = 0; k < NC; ++k) sum += expf(sp[k] - m);
        }
        sbox[a] = v;
        const float sl = scores[((size_t)b * A_N + a) * NC + c];
        const float sc = expf(sl - m) / sum;
        skeys[a] = (sc > 0.01f) ? pack_key(sc, (uint32_t)a) : ~0ull;
    }
    for (int i = A_N + t; i < SORT_N; i += THREADS) skeys[i] = ~0ull;
    if (t == 0) sW = 0;
    __syncthreads();

    uint64_t k[8];
    #pragma unroll
    for (int r = 0; r < 8; ++r) k[r] = skeys[(w << 9) + (r << 6) + l];
    for (int kk = 2; kk <= SORT_N; kk <<= 1) {
        for (int j = kk >> 1; j; j >>= 1) {
            if (j >= 512) {
                __syncthreads();
                #pragma unroll
                for (int r = 0; r < 8; ++r) skeys[(w << 9) + (r << 6) + l] = k[r];
                __syncthreads();
                #pragma unroll
                for (int r = 0; r < 8; ++r) {
                    const int e = (w << 9) + (r << 6) + l;
                    const uint64_t o = skeys[e ^ j];
                    const bool keep_min = (((e & j) == 0) == ((e & kk) == 0));
                    const uint64_t mn = k[r] < o ? k[r] : o;
                    const uint64_t mx = k[r] < o ? o : k[r];
                    k[r] = keep_min ? mn : mx;
                }
            } else if (j >= 64) {
                const int rb = j >> 6;
                #pragma unroll
                for (int r = 0; r < 8; ++r) {
                    if ((r & rb) == 0) {
                        const int p = r | rb;
                        const int e = (w << 9) + (r << 6) + l;
                        const bool up = ((e & kk) == 0);
                        const uint64_t x = k[r], y = k[p];
                        const uint64_t mn = x < y ? x : y;
                        const uint64_t mx = x < y ? y : x;
                        k[r] = up ? mn : mx;
                        k[p] = up ? mx : mn;
                    }
                }
            } else {
                #pragma unroll
                for (int r = 0; r < 8; ++r) {
                    const uint64_t o = (uint64_t)__shfl_xor((unsigned long long)k[r], j, 64);
                    const int e = (w << 9) + (r << 6) + l;
                    const bool keep_min = (((e & j) == 0) == ((e & kk) == 0));
                    const uint64_t mn = k[r] < o ? k[r] : o;
                    const uint64_t mx = k[r] < o ? o : k[r];
                    k[r] = keep_min ? mn : mx;
                }
            }
        }
    }
    __syncthreads();
    #pragma unroll
    for (int r = 0; r < 8; ++r) skeys[(w << 9) + (r << 6) + l] = k[r];
    __syncthreads();

    int W = 0;
    for (int cb = 0; cb < SORT_N; cb += CH) {
        if (skeys[cb] == ~0ull) break;
        if (t < CH) {
            const uint64_t kc = skeys[cb + t];
            const bool v = (kc != ~0ull);
            schunk[t] = v ? sbox[(uint32_t)kc] : make_float4(-8.f, -8.f, -8.f, -8.f);
            sdead[t]  = v ? 0 : 1;
        }
        __syncthreads();
        const float4 cb0 = schunk[l];
        const float4 cb1 = schunk[64 + l];
        const float  ca0 = box_area(cb0);
        const float  ca1 = box_area(cb1);
        for (int r = w * 32; r < w * 32 + 32; ++r) {
            const float4 rbx = schunk[r];
            const float  ra  = box_area(rbx);
            const uint64_t m0 = __ballot(iou_gt(rbx, ra, cb0, ca0));
            const uint64_t m1 = __ballot(iou_gt(rbx, ra, cb1, ca1));
            if (l == 0) { srow[r][0] = m0; srow[r][1] = m1; }
        }
        {
            const int jj = t >> 1, h = t & 1;
            const float4 bj = schunk[jj];
            const float  aj = box_area(bj);
            int sup = 0;
            for (int w2 = h; w2 < W; w2 += 2) {
                const float4 bw = swbox[w2];
                if (iou_gt(bw, box_area(bw), bj, aj)) { sup = 1; break; }
            }
            sup |= __shfl_xor(sup, 1, 64);
            if (h == 0 && sup) sdead[jj] = 1;
        }
        __syncthreads();
        if (t < 64) {
            bool al0 = !sdead[t];
            bool al1 = !sdead[64 + t];
            int Wl = W;
            while (true) {
                const unsigned long long bal0 = __ballot(al0);
                const unsigned long long bal1 = __ballot(al1);
                if (!(bal0 | bal1)) break;
                const int f = bal0 ? (__ffsll(bal0) - 1) : (64 + __ffsll(bal1) - 1);
                if (t == 0) { swkey[Wl] = skeys[cb + f]; swbox[Wl] = schunk[f]; }
                const uint64_t r0 = srow[f][0];
                const uint64_t r1 = srow[f][1];
                al0 = al0 && !((r0 >> t) & 1);
                al1 = al1 && !((r1 >> t) & 1);
                if (++Wl >= TOPK) break;
            }
            if (t == 0) sW = Wl;
        }
        __syncthreads();
        W = sW;
        if (W >= TOPK) break;
    }

    const uint32_t  base = (uint32_t)(c - 1) * A_N;
    uint64_t* const out  = ws_keys + ((size_t)b * CF + (c - 1)) * TOPK;
    for (int kx = t; kx < TOPK; kx += THREADS) {
        if (kx < W) {
            const uint64_t kk2 = swkey[kx];
            out[kx] = (kk2 & 0xFFFFFFFF00000000ull) | (uint64_t)(base + (uint32_t)kk2);
        } else {
            out[kx] = ~0ull;
        }
    }
}

// ---- merge: per batch top-200 of 20 sorted lists (R2/R3/R4-verified) ----
__global__ __launch_bounds__(THREADS)
void merge_kernel(const float* __restrict__ locs,
                  const float* __restrict__ anchors,
                  const uint64_t* __restrict__ ws_keys,
                  float* __restrict__ out)
{
    __shared__ uint64_t Abuf[20][256];
    __shared__ uint64_t Bbuf[10][256];

    const int b = blockIdx.x;
    const int t = threadIdx.x;
    const uint64_t* const in = ws_keys + (size_t)b * CF * TOPK;

    for (int e = t; e < CF * 256; e += THREADS) {
        const int c = e >> 8, i = e & 255;
        Abuf[c][i] = (i < TOPK) ? in[c * TOPK + i] : ~0ull;
    }

    uint64_t (*src)[256] = Abuf;
    uint64_t (*dst)[256] = Bbuf;
    int n = CF;
    while (n > 1) {
        const int  nm    = n >> 1;
        const bool carry = (n & 1) != 0;
        __syncthreads();
        for (int e = t; e < nm * 256; e += THREADS) {
            const int mm = e >> 8, i = e & 255;
            const uint64_t x = src[2 * mm][i];
            const uint64_t y = src[2 * mm + 1][255 - i];
            dst[mm][i] = x < y ? x : y;
        }
        if (carry)
            for (int i = t; i < 256; i += THREADS) dst[nm][i] = src[n - 1][i];
        for (int j = 128; j; j >>= 1) {
            __syncthreads();
            for (int pp = t; pp < nm * 128; pp += THREADS) {
                const int mm = pp >> 7, qq = pp & 127;
                const int i  = ((qq & ~(j - 1)) << 1) | (qq & (j - 1));
                const uint64_t x = dst[mm][i], y = dst[mm][i + j];
                if (y < x) { dst[mm][i] = y; dst[mm][i + j] = x; }
            }
        }
        uint64_t (*tmp)[256] = src; src = dst; dst = tmp;
        n = nm + (carry ? 1 : 0);
    }
    __syncthreads();

    if (t < TOPK) {
        const uint64_t k = src[0][t];
        float* const boxes_out  = out;
        float* const labels_out = out + (size_t)B_N * TOPK * 4;
        float* const scores_out = out + (size_t)B_N * TOPK * 5;
        const size_t s = (size_t)b * TOPK + t;
        if (k == ~0ull) {
            boxes_out[s * 4 + 0] = 0.0f;
            boxes_out[s * 4 + 1] = 0.0f;
            boxes_out[s * 4 + 2] = 0.0f;
            boxes_out[s * 4 + 3] = 0.0f;
            labels_out[s] = 0.0f;
            scores_out[s] = 0.0f;
        } else {
            const uint32_t flat = (uint32_t)k;
            const int cls = flat / A_N;
            const int a   = flat - cls * A_N;
            const float sc = __uint_as_float(~(uint32_t)(k >> 32));
            const float4 v = decode_box(((const float4*)locs)[(size_t)b * A_N + a],
                                        ((const float4*)anchors)[a]);
            boxes_out[s * 4 + 0] = v.x;
            boxes_out[s * 4 + 1] = v.y;
            boxes_out[s * 4 + 2] = v.z;
            boxes_out[s * 4 + 3] = v.w;
            labels_out[s] = (float)(cls + 1);
            scores_out[s] = sc;
        }
    }
}

extern "C" void kernel_launch(void* const* d_in, const int* in_sizes, int n_in,
                              void* d_out, int out_size, void* d_ws, size_t ws_size,
                              hipStream_t stream) {
    const float* locs    = (const float*)d_in[0];
    const float* scores  = (const float*)d_in[1];
    const float* anchors = (const float*)d_in[2];
    uint64_t*       ws_keys  = (uint64_t*)d_ws;
    float4*         boxes_ws = (float4*)((char*)d_ws + BOX_OFF);
    float2*         ms_ws    = (float2*)((char*)d_ws + MS_OFF);
    unsigned short* ranks_ws = (unsigned short*)((char*)d_ws + RANKS_OFF);
    float*          outp     = (float*)d_out;

    if (ws_size >= WS_A_BYTES) {
        hipLaunchKernelGGL(prep_kernel, dim3((B_N * A_N + THREADS - 1) / THREADS),
                           dim3(THREADS), 0, stream, locs, scores, anchors, boxes_ws, ms_ws);
        hipLaunchKernelGGL(sort_kernel, dim3(B_N * CF), dim3(THREADS), 0, stream,
                           scores, ms_ws, ranks_ws);
        hipLaunchKernelGGL(chunk_nms_kernel, dim3(B_N * CF), dim3(THREADS), 0, stream,
                           scores, ms_ws, boxes_ws, ranks_ws, ws_keys);
    } else if (ws_size >= WS_B_BYTES) {
        hipLaunchKernelGGL(prep_kernel, dim3((B_N * A_N + THREADS - 1) / THREADS),
                           dim3(THREADS), 0, stream, locs, scores, anchors, boxes_ws, ms_ws);
        hipLaunchKernelGGL((nms_mono<true>), dim3(B_N * CF), dim3(THREADS), 0, stream,
                           locs, scores, anchors, boxes_ws, ms_ws, ws_keys);
    } else {
        hipLaunchKernelGGL((nms_mono<false>), dim3(B_N * CF), dim3(THREADS), 0, stream,
                           locs, scores, anchors, boxes_ws, ms_ws, ws_keys);
    }
    hipLaunchKernelGGL(merge_kernel, dim3(B_N), dim3(THREADS), 0, stream,
                       locs, anchors, ws_keys, outp);
}

// Round 6
// 250.457 us; speedup vs baseline: 1.1483x; 1.1483x over previous
//
#include <hip/hip_runtime.h>
#include <stdint.h>

// DetectionBaseline: SSD post-process. R6: phase-B restructured for throughput —
//  column build via intra-wave shuffles (no LDS), cross-test unrolled w/o early exit
//  (independent uniform LDS loads). Resolve (register kill-columns) unchanged from R5.
//   prep      : per (b,a) box decode + softmax (m,sum)
//   sort      : per (b,c) key build + register bitonic sort -> u16 rank list
//   chunk_nms : per (b,c) chunked greedy NMS -> kept key lists
//   merge     : per b truncated pairwise bitonic merges -> top-200 output

#define A_N     1280
#define CF      20
#define NC      21
#define B_N     16
#define TOPK    200
#define THREADS 256
#define SORT_N  2048
#define CH      128

// ws layout (bytes)
#define KEYS_BYTES   (B_N * CF * TOPK * 8)                 // 512000 kept-key lists
#define BOX_OFF      KEYS_BYTES                             // float4 [16*1280] = 327680
#define MS_OFF       (BOX_OFF + B_N * A_N * 16)             // float2 [16*1280] = 163840
#define RANKS_OFF    (MS_OFF + B_N * A_N * 8)               // u16 [320*1280]   = 819200
#define WS_B_BYTES   RANKS_OFF                              // 1003520 (mono-prep tier)
#define WS_A_BYTES   (RANKS_OFF + (size_t)B_N * CF * A_N * 2)  // 1822720 (split tier)

static __device__ __forceinline__ uint64_t pack_key(float sc, uint32_t idx) {
    // softmax scores positive -> float bits monotone. ~bits => ascending key = descending
    // score; low 32 bits = index => ties break toward smaller index (stable argsort / top_k).
    return ((uint64_t)(uint32_t)(~__float_as_uint(sc)) << 32) | (uint64_t)idx;
}

static __device__ __forceinline__ float box_area(const float4 v) {
    return (v.z - v.x) * (v.w - v.y);
}

static __device__ __forceinline__ bool iou_gt(const float4 a, const float aarea,
                                              const float4 b, const float barea) {
    // ref-exact: inter/(area_row + area_col - inter) > 0.45
    const float lx = fmaxf(a.x, b.x);
    const float ly = fmaxf(a.y, b.y);
    const float rx = fminf(a.z, b.z);
    const float ry = fminf(a.w, b.w);
    const float wx = fmaxf(rx - lx, 0.0f);
    const float wy = fmaxf(ry - ly, 0.0f);
    const float inter = wx * wy;
    const float uni   = aarea + barea - inter;
    return inter / uni > 0.45f;
}

static __device__ __forceinline__ float4 decode_box(const float4 lc, const float4 an) {
    const float cx = lc.x * an.z / 10.0f + an.x;
    const float cy = lc.y * an.w / 10.0f + an.y;
    const float w  = expf(lc.z / 5.0f) * an.z;
    const float h  = expf(lc.w / 5.0f) * an.w;
    float4 v;
    v.x = cx - w / 2.0f; v.y = cy - h / 2.0f;
    v.z = cx + w / 2.0f; v.w = cy + h / 2.0f;
    return v;
}

static __device__ __forceinline__ float4 shfl_box(const float4 v, int lane) {
    float4 r;
    r.x = __shfl(v.x, lane, 64);
    r.y = __shfl(v.y, lane, 64);
    r.z = __shfl(v.z, lane, 64);
    r.w = __shfl(v.w, lane, 64);
    return r;
}

// ---- prep: per (b,a) decoded box + softmax (max, sum) ----
__global__ __launch_bounds__(THREADS)
void prep_kernel(const float* __restrict__ locs,
                 const float* __restrict__ scores,
                 const float* __restrict__ anchors,
                 float4* __restrict__ boxes_ws,
                 float2* __restrict__ ms_ws)
{
    const int g = blockIdx.x * THREADS + threadIdx.x;
    if (g >= B_N * A_N) return;
    const int a = g % A_N;
    boxes_ws[g] = decode_box(((const float4*)locs)[g], ((const float4*)anchors)[a]);
    const float* sp = scores + (size_t)g * NC;
    float m = sp[0];
    #pragma unroll
    for (int k = 1; k < NC; ++k) m = fmaxf(m, sp[k]);
    float sum = 0.0f;
    #pragma unroll
    for (int k = 0; k < NC; ++k) sum += expf(sp[k] - m);
    ms_ws[g] = make_float2(m, sum);
}

// ---- sort: per (b,c) build keys, register bitonic sort, emit u16 rank list ----
__global__ __launch_bounds__(THREADS)
void sort_kernel(const float* __restrict__ scores,
                 const float2* __restrict__ ms_ws,
                 unsigned short* __restrict__ ranks_ws)
{
    __shared__ uint64_t skeys[SORT_N];   // 16 KB

    const int blk = blockIdx.x;
    const int b   = blk / CF;
    const int c   = blk % CF + 1;
    const int t   = threadIdx.x;
    const int l   = t & 63;
    const int w   = t >> 6;

    #pragma unroll
    for (int i = 0; i < A_N / THREADS; ++i) {
        const int a = t + i * THREADS;
        const float2 ms = ms_ws[b * A_N + a];
        const float  sl = scores[((size_t)b * A_N + a) * NC + c];
        const float  sc = expf(sl - ms.x) / ms.y;          // ref-exact softmax value
        skeys[a] = (sc > 0.01f) ? pack_key(sc, (uint32_t)a) : ~0ull;
    }
    for (int i = A_N + t; i < SORT_N; i += THREADS) skeys[i] = ~0ull;
    __syncthreads();

    // register/wave bitonic sort, element e = w*512 + r*64 + l (R4/R5-verified)
    uint64_t k[8];
    #pragma unroll
    for (int r = 0; r < 8; ++r) k[r] = skeys[(w << 9) + (r << 6) + l];

    for (int kk = 2; kk <= SORT_N; kk <<= 1) {
        for (int j = kk >> 1; j; j >>= 1) {
            if (j >= 512) {
                __syncthreads();
                #pragma unroll
                for (int r = 0; r < 8; ++r) skeys[(w << 9) + (r << 6) + l] = k[r];
                __syncthreads();
                #pragma unroll
                for (int r = 0; r < 8; ++r) {
                    const int e = (w << 9) + (r << 6) + l;
                    const uint64_t o = skeys[e ^ j];
                    const bool keep_min = (((e & j) == 0) == ((e & kk) == 0));
                    const uint64_t mn = k[r] < o ? k[r] : o;
                    const uint64_t mx = k[r] < o ? o : k[r];
                    k[r] = keep_min ? mn : mx;
                }
            } else if (j >= 64) {
                const int rb = j >> 6;
                #pragma unroll
                for (int r = 0; r < 8; ++r) {
                    if ((r & rb) == 0) {
                        const int p = r | rb;
                        const int e = (w << 9) + (r << 6) + l;
                        const bool up = ((e & kk) == 0);
                        const uint64_t x = k[r], y = k[p];
                        const uint64_t mn = x < y ? x : y;
                        const uint64_t mx = x < y ? y : x;
                        k[r] = up ? mn : mx;
                        k[p] = up ? mx : mn;
                    }
                }
            } else {
                #pragma unroll
                for (int r = 0; r < 8; ++r) {
                    const uint64_t o = (uint64_t)__shfl_xor((unsigned long long)k[r], j, 64);
                    const int e = (w << 9) + (r << 6) + l;
                    const bool keep_min = (((e & j) == 0) == ((e & kk) == 0));
                    const uint64_t mn = k[r] < o ? k[r] : o;
                    const uint64_t mx = k[r] < o ? o : k[r];
                    k[r] = keep_min ? mn : mx;
                }
            }
        }
    }
    // valid candidates <= 1280 -> ranks >= 1280 all-invalid: store first 1280 only
    unsigned short* const dst = ranks_ws + (size_t)blk * A_N;
    #pragma unroll
    for (int r = 0; r < 8; ++r) {
        const int e = (w << 9) + (r << 6) + l;
        if (e < A_N)
            dst[e] = (k[r] == ~0ull) ? (unsigned short)0xFFFF
                                     : (unsigned short)(k[r] & 0xFFFF);
    }
}

// ---- chunk_nms: greedy NMS; column build via shuffles, cross-test unrolled ----
__global__ __launch_bounds__(THREADS)
void chunk_nms_kernel(const float* __restrict__ scores,
                      const float2* __restrict__ ms_ws,
                      const float4* __restrict__ boxes_ws,
                      const unsigned short* __restrict__ ranks_ws,
                      uint64_t* __restrict__ ws_keys)
{
    __shared__ unsigned short sranks[A_N];   // 2.5 KB
    __shared__ float4         schunk[CH];    // 2 KB
    __shared__ uint64_t       scolB[64][2];  // wave-1 column halves (1 KB)
    __shared__ unsigned char  sdead[CH];
    __shared__ float4         swbox[TOPK];   // winner boxes (cross-test)
    __shared__ unsigned short swidx[TOPK];   // winner anchor ids (rank order)
    __shared__ int            sW;

    const int blk = blockIdx.x;
    const int b   = blk / CF;
    const int c   = blk % CF + 1;
    const int t   = threadIdx.x;
    const int l   = t & 63;
    const int w   = t >> 6;

    const unsigned short* const rsrc = ranks_ws + (size_t)blk * A_N;
    for (int i = t; i < A_N; i += THREADS) sranks[i] = rsrc[i];
    if (t == 0) sW = 0;
    __syncthreads();

    int W = 0;
    for (int cb = 0; cb < A_N; cb += CH) {
        if (sranks[cb] == 0xFFFF) break;      // sorted: rest invalid (uniform)

        // phase A: gather chunk boxes
        if (t < CH) {
            const unsigned short rk = sranks[cb + t];
            schunk[t] = (rk != 0xFFFF) ? boxes_ws[(size_t)b * A_N + rk]
                                       : make_float4(-8.f, -8.f, -8.f, -8.f);
        }
        __syncthreads();

        const float4 box_lo = schunk[l];       // coalesced, 2-way alias free
        const float4 box_hi = schunk[64 + l];

        // phase B: waves 0/1 build kill-columns via intra-wave shuffles (no LDS);
        //          waves 2/3 cross-test vs prior winners (unrolled, no early exit)
        uint64_t c0 = 0, c1 = 0;   // wave 0: rows [0,64) of col l / col 64+l
        if (w < 2) {
            const float  al = box_area(box_lo);
            const float  ah = box_area(box_hi);
            const float4 rowsrc = (w == 0) ? box_lo : box_hi;  // rows 0-63 / 64-127
            uint64_t m0 = 0, m1 = 0;
            #pragma unroll 8
            for (int j = 0; j < 64; ++j) {
                const float4 rbx = shfl_box(rowsrc, j);
                const float  ra  = box_area(rbx);
                m0 |= (uint64_t)(iou_gt(rbx, ra, box_lo, al) ? 1 : 0) << j;
                m1 |= (uint64_t)(iou_gt(rbx, ra, box_hi, ah) ? 1 : 0) << j;
            }
            if (w == 1) { scolB[l][0] = m0; scolB[l][1] = m1; }
            else        { c0 = m0; c1 = m1; }
        } else {
            const int    x   = (w == 2) ? l : 64 + l;
            const float4 bxv = (w == 2) ? box_lo : box_hi;
            const float  ax  = box_area(bxv);
            int dead = (sranks[cb + x] == 0xFFFF) ? 1 : 0;
            #pragma unroll 4
            for (int i = 0; i < W; ++i) {       // no early exit -> loads pipeline
                const float4 bw = swbox[i];     // uniform LDS broadcast
                dead |= iou_gt(bw, box_area(bw), bxv, ax) ? 1 : 0;
            }
            sdead[x] = (unsigned char)dead;
        }
        __syncthreads();

        // phase C: wave 0 resolves chunk in rank order -- register-only chain (R5-verified)
        if (w == 0) {
            const uint64_t h0 = scolB[l][0];   // rows [64,128) of col l
            const uint64_t h1 = scolB[l][1];   // rows [64,128) of col 64+l
            const unsigned short rk0 = sranks[cb + l];
            const unsigned short rk1 = sranks[cb + 64 + l];
            bool a0 = !sdead[l];
            bool a1 = !sdead[64 + l];
            int Wl = W;
            while (true) {
                const unsigned long long b0 = __ballot(a0);
                const unsigned long long b1 = __ballot(a1);
                if (!(b0 | b1)) break;
                const int f = b0 ? (__ffsll(b0) - 1) : (64 + __ffsll(b1) - 1);
                if (f < 64) {
                    if (l == f)      { swidx[Wl] = rk0; swbox[Wl] = box_lo; }
                } else {
                    if (l == f - 64) { swidx[Wl] = rk1; swbox[Wl] = box_hi; }
                }
                uint32_t k0, k1;
                if (f < 64) { k0 = (uint32_t)(c0 >> f) & 1;        k1 = (uint32_t)(c1 >> f) & 1; }
                else        { k0 = (uint32_t)(h0 >> (f - 64)) & 1; k1 = (uint32_t)(h1 >> (f - 64)) & 1; }
                a0 = a0 && !k0;                 // winner self-clears (IoU=1)
                a1 = a1 && !k1;
                if (++Wl >= TOPK) break;        // later winners can't reach output
            }
            if (l == 0) sW = Wl;
        }
        __syncthreads();
        W = sW;
        if (W >= TOPK) break;
    }

    // epilogue: reconstruct keys (bitwise == sort_kernel's) and write kept list
    const uint32_t  base = (uint32_t)(c - 1) * A_N;
    uint64_t* const out  = ws_keys + ((size_t)b * CF + (c - 1)) * TOPK;
    for (int k2 = t; k2 < TOPK; k2 += THREADS) {
        if (k2 < W) {
            const int a = swidx[k2];
            const float2 ms = ms_ws[(size_t)b * A_N + a];
            const float  sc = expf(scores[((size_t)b * A_N + a) * NC + c] - ms.x) / ms.y;
            out[k2] = ((uint64_t)(uint32_t)(~__float_as_uint(sc)) << 32)
                    | (uint64_t)(base + (uint32_t)a);
        } else {
            out[k2] = ~0ull;
        }
    }
}

// ---- mono fallback (R4 kernel, verified) for small ws ----
template <bool PREP>
__global__ __launch_bounds__(THREADS)
void nms_mono(const float* __restrict__ locs,
              const float* __restrict__ scores,
              const float* __restrict__ anchors,
              const float4* __restrict__ boxes_ws,
              const float2* __restrict__ ms_ws,
              uint64_t* __restrict__ ws_keys)
{
    __shared__ uint64_t      skeys[SORT_N];
    __shared__ float4        sbox[A_N];
    __shared__ float4        schunk[CH];
    __shared__ uint64_t      srow[CH][2];
    __shared__ float4        swbox[TOPK];
    __shared__ uint64_t      swkey[TOPK];
    __shared__ unsigned char sdead[CH];
    __shared__ int           sW;

    const int blk = blockIdx.x;
    const int b   = blk / CF;
    const int c   = blk % CF + 1;
    const int t   = threadIdx.x;
    const int l   = t & 63;
    const int w   = t >> 6;

    #pragma unroll
    for (int i = 0; i < A_N / THREADS; ++i) {
        const int a = t + i * THREADS;
        float4 v; float m, sum;
        if (PREP) {
            v = boxes_ws[b * A_N + a];
            const float2 ms = ms_ws[b * A_N + a];
            m = ms.x; sum = ms.y;
        } else {
            v = decode_box(((const float4*)locs)[(size_t)b * A_N + a],
                           ((const float4*)anchors)[a]);
            const float* sp = scores + ((size_t)b * A_N + a) * NC;
            m = sp[0];
            #pragma unroll
            for (int k = 1; k < NC; ++k) m = fmaxf(m, sp[k]);
            sum = 0.0f;
            #pragma unroll
            for (int k = 0; k < NC; ++k) sum += expf(sp[k] - m);
        }
        sbox[a] = v;
        const float sl = scores[((size_t)b * A_N + a) * NC + c];
        const float sc = expf(sl - m) / sum;
        skeys[a] = (sc > 0.01f) ? pack_key(sc, (uint32_t)a) : ~0ull;
    }
    for (int i = A_N + t; i < SORT_N; i += THREADS) skeys[i] = ~0ull;
    if (t == 0) sW = 0;
    __syncthreads();

    uint64_t k[8];
    #pragma unroll
    for (int r = 0; r < 8; ++r) k[r] = skeys[(w << 9) + (r << 6) + l];
    for (int kk = 2; kk <= SORT_N; kk <<= 1) {
        for (int j = kk >> 1; j; j >>= 1) {
            if (j >= 512) {
                __syncthreads();
                #pragma unroll
                for (int r = 0; r < 8; ++r) skeys[(w << 9) + (r << 6) + l] = k[r];
                __syncthreads();
                #pragma unroll
                for (int r = 0; r < 8; ++r) {
                    const int e = (w << 9) + (r << 6) + l;
                    const uint64_t o = skeys[e ^ j];
                    const bool keep_min = (((e & j) == 0) == ((e & kk) == 0));
                    const uint64_t mn = k[r] < o ? k[r] : o;
                    const uint64_t mx = k[r] < o ? o : k[r];
                    k[r] = keep_min ? mn : mx;
                }
            } else if (j >= 64) {
                const int rb = j >> 6;
                #pragma unroll
                for (int r = 0; r < 8; ++r) {
                    if ((r & rb) == 0) {
                        const int p = r | rb;
                        const int e = (w << 9) + (r << 6) + l;
                        const bool up = ((e & kk) == 0);
                        const uint64_t x = k[r], y = k[p];
                        const uint64_t mn = x < y ? x : y;
                        const uint64_t mx = x < y ? y : x;
                        k[r] = up ? mn : mx;
                        k[p] = up ? mx : mn;
                    }
                }
            } else {
                #pragma unroll
                for (int r = 0; r < 8; ++r) {
                    const uint64_t o = (uint64_t)__shfl_xor((unsigned long long)k[r], j, 64);
                    const int e = (w << 9) + (r << 6) + l;
                    const bool keep_min = (((e & j) == 0) == ((e & kk) == 0));
                    const uint64_t mn = k[r] < o ? k[r] : o;
                    const uint64_t mx = k[r] < o ? o : k[r];
                    k[r] = keep_min ? mn : mx;
                }
            }
        }
    }
    __syncthreads();
    #pragma unroll
    for (int r = 0; r < 8; ++r) skeys[(w << 9) + (r << 6) + l] = k[r];
    __syncthreads();

    int W = 0;
    for (int cb = 0; cb < SORT_N; cb += CH) {
        if (skeys[cb] == ~0ull) break;
        if (t < CH) {
            const uint64_t kc = skeys[cb + t];
            const bool v = (kc != ~0ull);
            schunk[t] = v ? sbox[(uint32_t)kc] : make_float4(-8.f, -8.f, -8.f, -8.f);
            sdead[t]  = v ? 0 : 1;
        }
        __syncthreads();
        const float4 cb0 = schunk[l];
        const float4 cb1 = schunk[64 + l];
        const float  ca0 = box_area(cb0);
        const float  ca1 = box_area(cb1);
        for (int r = w * 32; r < w * 32 + 32; ++r) {
            const float4 rbx = schunk[r];
            const float  ra  = box_area(rbx);
            const uint64_t m0 = __ballot(iou_gt(rbx, ra, cb0, ca0));
            const uint64_t m1 = __ballot(iou_gt(rbx, ra, cb1, ca1));
            if (l == 0) { srow[r][0] = m0; srow[r][1] = m1; }
        }
        {
            const int jj = t >> 1, h = t & 1;
            const float4 bj = schunk[jj];
            const float  aj = box_area(bj);
            int sup = 0;
            for (int w2 = h; w2 < W; w2 += 2) {
                const float4 bw = swbox[w2];
                if (iou_gt(bw, box_area(bw), bj, aj)) { sup = 1; break; }
            }
            sup |= __shfl_xor(sup, 1, 64);
            if (h == 0 && sup) sdead[jj] = 1;
        }
        __syncthreads();
        if (t < 64) {
            bool al0 = !sdead[t];
            bool al1 = !sdead[64 + t];
            int Wl = W;
            while (true) {
                const unsigned long long bal0 = __ballot(al0);
                const unsigned long long bal1 = __ballot(al1);
                if (!(bal0 | bal1)) break;
                const int f = bal0 ? (__ffsll(bal0) - 1) : (64 + __ffsll(bal1) - 1);
                if (t == 0) { swkey[Wl] = skeys[cb + f]; swbox[Wl] = schunk[f]; }
                const uint64_t r0 = srow[f][0];
                const uint64_t r1 = srow[f][1];
                al0 = al0 && !((r0 >> t) & 1);
                al1 = al1 && !((r1 >> t) & 1);
                if (++Wl >= TOPK) break;
            }
            if (t == 0) sW = Wl;
        }
        __syncthreads();
        W = sW;
        if (W >= TOPK) break;
    }

    const uint32_t  base = (uint32_t)(c - 1) * A_N;
    uint64_t* const out  = ws_keys + ((size_t)b * CF + (c - 1)) * TOPK;
    for (int kx = t; kx < TOPK; kx += THREADS) {
        if (kx < W) {
            const uint64_t kk2 = swkey[kx];
            out[kx] = (kk2 & 0xFFFFFFFF00000000ull) | (uint64_t)(base + (uint32_t)kk2);
        } else {
            out[kx] = ~0ull;
        }
    }
}

// ---- merge: per batch top-200 of 20 sorted lists (R2..R5-verified) ----
__global__ __launch_bounds__(THREADS)
void merge_kernel(const float* __restrict__ locs,
                  const float* __restrict__ anchors,
                  const uint64_t* __restrict__ ws_keys,
                  float* __restrict__ out)
{
    __shared__ uint64_t Abuf[20][256];
    __shared__ uint64_t Bbuf[10][256];

    const int b = blockIdx.x;
    const int t = threadIdx.x;
    const uint64_t* const in = ws_keys + (size_t)b * CF * TOPK;

    for (int e = t; e < CF * 256; e += THREADS) {
        const int c = e >> 8, i = e & 255;
        Abuf[c][i] = (i < TOPK) ? in[c * TOPK + i] : ~0ull;
    }

    uint64_t (*src)[256] = Abuf;
    uint64_t (*dst)[256] = Bbuf;
    int n = CF;
    while (n > 1) {
        const int  nm    = n >> 1;
        const bool carry = (n & 1) != 0;
        __syncthreads();
        for (int e = t; e < nm * 256; e += THREADS) {
            const int mm = e >> 8, i = e & 255;
            const uint64_t x = src[2 * mm][i];
            const uint64_t y = src[2 * mm + 1][255 - i];
            dst[mm][i] = x < y ? x : y;
        }
        if (carry)
            for (int i = t; i < 256; i += THREADS) dst[nm][i] = src[n - 1][i];
        for (int j = 128; j; j >>= 1) {
            __syncthreads();
            for (int pp = t; pp < nm * 128; pp += THREADS) {
                const int mm = pp >> 7, qq = pp & 127;
                const int i  = ((qq & ~(j - 1)) << 1) | (qq & (j - 1));
                const uint64_t x = dst[mm][i], y = dst[mm][i + j];
                if (y < x) { dst[mm][i] = y; dst[mm][i + j] = x; }
            }
        }
        uint64_t (*tmp)[256] = src; src = dst; dst = tmp;
        n = nm + (carry ? 1 : 0);
    }
    __syncthreads();

    if (t < TOPK) {
        const uint64_t k = src[0][t];
        float* const boxes_out  = out;
        float* const labels_out = out + (size_t)B_N * TOPK * 4;
        float* const scores_out = out + (size_t)B_N * TOPK * 5;
        const size_t s = (size_t)b * TOPK + t;
        if (k == ~0ull) {
            boxes_out[s * 4 + 0] = 0.0f;
            boxes_out[s * 4 + 1] = 0.0f;
            boxes_out[s * 4 + 2] = 0.0f;
            boxes_out[s * 4 + 3] = 0.0f;
            labels_out[s] = 0.0f;
            scores_out[s] = 0.0f;
        } else {
            const uint32_t flat = (uint32_t)k;
            const int cls = flat / A_N;
            const int a   = flat - cls * A_N;
            const float sc = __uint_as_float(~(uint32_t)(k >> 32));
            const float4 v = decode_box(((const float4*)locs)[(size_t)b * A_N + a],
                                        ((const float4*)anchors)[a]);
            boxes_out[s * 4 + 0] = v.x;
            boxes_out[s * 4 + 1] = v.y;
            boxes_out[s * 4 + 2] = v.z;
            boxes_out[s * 4 + 3] = v.w;
            labels_out[s] = (float)(cls + 1);
            scores_out[s] = sc;
        }
    }
}

extern "C" void kernel_launch(void* const* d_in, const int* in_sizes, int n_in,
                              void* d_out, int out_size, void* d_ws, size_t ws_size,
                              hipStream_t stream) {
    const float* locs    = (const float*)d_in[0];
    const float* scores  = (const float*)d_in[1];
    const float* anchors = (const float*)d_in[2];
    uint64_t*       ws_keys  = (uint64_t*)d_ws;
    float4*         boxes_ws = (float4*)((char*)d_ws + BOX_OFF);
    float2*         ms_ws    = (float2*)((char*)d_ws + MS_OFF);
    unsigned short* ranks_ws = (unsigned short*)((char*)d_ws + RANKS_OFF);
    float*          outp     = (float*)d_out;

    if (ws_size >= WS_A_BYTES) {
        hipLaunchKernelGGL(prep_kernel, dim3((B_N * A_N + THREADS - 1) / THREADS),
                           dim3(THREADS), 0, stream, locs, scores, anchors, boxes_ws, ms_ws);
        hipLaunchKernelGGL(sort_kernel, dim3(B_N * CF), dim3(THREADS), 0, stream,
                           scores, ms_ws, ranks_ws);
        hipLaunchKernelGGL(chunk_nms_kernel, dim3(B_N * CF), dim3(THREADS), 0, stream,
                           scores, ms_ws, boxes_ws, ranks_ws, ws_keys);
    } else if (ws_size >= WS_B_BYTES) {
        hipLaunchKernelGGL(prep_kernel, dim3((B_N * A_N + THREADS - 1) / THREADS),
                           dim3(THREADS), 0, stream, locs, scores, anchors, boxes_ws, ms_ws);
        hipLaunchKernelGGL((nms_mono<true>), dim3(B_N * CF), dim3(THREADS), 0, stream,
                           locs, scores, anchors, boxes_ws, ms_ws, ws_keys);
    } else {
        hipLaunchKernelGGL((nms_mono<false>), dim3(B_N * CF), dim3(THREADS), 0, stream,
                           locs, scores, anchors, boxes_ws, ms_ws, ws_keys);
    }
    hipLaunchKernelGGL(merge_kernel, dim3(B_N), dim3(THREADS), 0, stream,
                       locs, anchors, ws_keys, outp);
}

// Round 7
// 188.086 us; speedup vs baseline: 1.5291x; 1.3316x over previous
//
#include <hip/hip_runtime.h>
#include <stdint.h>

// DetectionBaseline: SSD post-process. R7: chunk_nms widened to 512 threads (8 waves):
//  - cross-test: 4 helpers per box (stripe winners, shfl-OR)
//  - matrix build: 16 rows/wave, sparse over alive-rows only (ballot+ffs loop)
//  - resolve: wave-0 register kill-columns (assembled from 8 per-wave u32 partials)
// prep / sort / merge / mono-fallback unchanged from R6 (verified absmax 0.0).

#define A_N     1280
#define CF      20
#define NC      21
#define B_N     16
#define TOPK    200
#define THREADS 256
#define CTHREADS 512
#define SORT_N  2048
#define CH      128

// ws layout (bytes)
#define KEYS_BYTES   (B_N * CF * TOPK * 8)                 // 512000 kept-key lists
#define BOX_OFF      KEYS_BYTES                             // float4 [16*1280] = 327680
#define MS_OFF       (BOX_OFF + B_N * A_N * 16)             // float2 [16*1280] = 163840
#define RANKS_OFF    (MS_OFF + B_N * A_N * 8)               // u16 [320*1280]   = 819200
#define WS_B_BYTES   RANKS_OFF                              // 1003520 (mono-prep tier)
#define WS_A_BYTES   (RANKS_OFF + (size_t)B_N * CF * A_N * 2)  // 1822720 (split tier)

static __device__ __forceinline__ uint64_t pack_key(float sc, uint32_t idx) {
    // softmax scores positive -> float bits monotone. ~bits => ascending key = descending
    // score; low 32 bits = index => ties break toward smaller index (stable argsort / top_k).
    return ((uint64_t)(uint32_t)(~__float_as_uint(sc)) << 32) | (uint64_t)idx;
}

static __device__ __forceinline__ float box_area(const float4 v) {
    return (v.z - v.x) * (v.w - v.y);
}

static __device__ __forceinline__ bool iou_gt(const float4 a, const float aarea,
                                              const float4 b, const float barea) {
    // ref-exact: inter/(area_row + area_col - inter) > 0.45
    const float lx = fmaxf(a.x, b.x);
    const float ly = fmaxf(a.y, b.y);
    const float rx = fminf(a.z, b.z);
    const float ry = fminf(a.w, b.w);
    const float wx = fmaxf(rx - lx, 0.0f);
    const float wy = fmaxf(ry - ly, 0.0f);
    const float inter = wx * wy;
    const float uni   = aarea + barea - inter;
    return inter / uni > 0.45f;
}

static __device__ __forceinline__ float4 decode_box(const float4 lc, const float4 an) {
    const float cx = lc.x * an.z / 10.0f + an.x;
    const float cy = lc.y * an.w / 10.0f + an.y;
    const float w  = expf(lc.z / 5.0f) * an.z;
    const float h  = expf(lc.w / 5.0f) * an.w;
    float4 v;
    v.x = cx - w / 2.0f; v.y = cy - h / 2.0f;
    v.z = cx + w / 2.0f; v.w = cy + h / 2.0f;
    return v;
}

static __device__ __forceinline__ float4 shfl_box(const float4 v, int lane) {
    float4 r;
    r.x = __shfl(v.x, lane, 64);
    r.y = __shfl(v.y, lane, 64);
    r.z = __shfl(v.z, lane, 64);
    r.w = __shfl(v.w, lane, 64);
    return r;
}

// ---- prep: per (b,a) decoded box + softmax (max, sum) ----
__global__ __launch_bounds__(THREADS)
void prep_kernel(const float* __restrict__ locs,
                 const float* __restrict__ scores,
                 const float* __restrict__ anchors,
                 float4* __restrict__ boxes_ws,
                 float2* __restrict__ ms_ws)
{
    const int g = blockIdx.x * THREADS + threadIdx.x;
    if (g >= B_N * A_N) return;
    const int a = g % A_N;
    boxes_ws[g] = decode_box(((const float4*)locs)[g], ((const float4*)anchors)[a]);
    const float* sp = scores + (size_t)g * NC;
    float m = sp[0];
    #pragma unroll
    for (int k = 1; k < NC; ++k) m = fmaxf(m, sp[k]);
    float sum = 0.0f;
    #pragma unroll
    for (int k = 0; k < NC; ++k) sum += expf(sp[k] - m);
    ms_ws[g] = make_float2(m, sum);
}

// ---- sort: per (b,c) build keys, register bitonic sort, emit u16 rank list ----
__global__ __launch_bounds__(THREADS)
void sort_kernel(const float* __restrict__ scores,
                 const float2* __restrict__ ms_ws,
                 unsigned short* __restrict__ ranks_ws)
{
    __shared__ uint64_t skeys[SORT_N];   // 16 KB

    const int blk = blockIdx.x;
    const int b   = blk / CF;
    const int c   = blk % CF + 1;
    const int t   = threadIdx.x;
    const int l   = t & 63;
    const int w   = t >> 6;

    #pragma unroll
    for (int i = 0; i < A_N / THREADS; ++i) {
        const int a = t + i * THREADS;
        const float2 ms = ms_ws[b * A_N + a];
        const float  sl = scores[((size_t)b * A_N + a) * NC + c];
        const float  sc = expf(sl - ms.x) / ms.y;          // ref-exact softmax value
        skeys[a] = (sc > 0.01f) ? pack_key(sc, (uint32_t)a) : ~0ull;
    }
    for (int i = A_N + t; i < SORT_N; i += THREADS) skeys[i] = ~0ull;
    __syncthreads();

    // register/wave bitonic sort, element e = w*512 + r*64 + l (R4..R6-verified)
    uint64_t k[8];
    #pragma unroll
    for (int r = 0; r < 8; ++r) k[r] = skeys[(w << 9) + (r << 6) + l];

    for (int kk = 2; kk <= SORT_N; kk <<= 1) {
        for (int j = kk >> 1; j; j >>= 1) {
            if (j >= 512) {
                __syncthreads();
                #pragma unroll
                for (int r = 0; r < 8; ++r) skeys[(w << 9) + (r << 6) + l] = k[r];
                __syncthreads();
                #pragma unroll
                for (int r = 0; r < 8; ++r) {
                    const int e = (w << 9) + (r << 6) + l;
                    const uint64_t o = skeys[e ^ j];
                    const bool keep_min = (((e & j) == 0) == ((e & kk) == 0));
                    const uint64_t mn = k[r] < o ? k[r] : o;
                    const uint64_t mx = k[r] < o ? o : k[r];
                    k[r] = keep_min ? mn : mx;
                }
            } else if (j >= 64) {
                const int rb = j >> 6;
                #pragma unroll
                for (int r = 0; r < 8; ++r) {
                    if ((r & rb) == 0) {
                        const int p = r | rb;
                        const int e = (w << 9) + (r << 6) + l;
                        const bool up = ((e & kk) == 0);
                        const uint64_t x = k[r], y = k[p];
                        const uint64_t mn = x < y ? x : y;
                        const uint64_t mx = x < y ? y : x;
                        k[r] = up ? mn : mx;
                        k[p] = up ? mx : mn;
                    }
                }
            } else {
                #pragma unroll
                for (int r = 0; r < 8; ++r) {
                    const uint64_t o = (uint64_t)__shfl_xor((unsigned long long)k[r], j, 64);
                    const int e = (w << 9) + (r << 6) + l;
                    const bool keep_min = (((e & j) == 0) == ((e & kk) == 0));
                    const uint64_t mn = k[r] < o ? k[r] : o;
                    const uint64_t mx = k[r] < o ? o : k[r];
                    k[r] = keep_min ? mn : mx;
                }
            }
        }
    }
    // valid candidates <= 1280 -> ranks >= 1280 all-invalid: store first 1280 only
    unsigned short* const dst = ranks_ws + (size_t)blk * A_N;
    #pragma unroll
    for (int r = 0; r < 8; ++r) {
        const int e = (w << 9) + (r << 6) + l;
        if (e < A_N)
            dst[e] = (k[r] == ~0ull) ? (unsigned short)0xFFFF
                                     : (unsigned short)(k[r] & 0xFFFF);
    }
}

// ---- chunk_nms (512 threads): cross-test 4 helpers/box, sparse alive-row build ----
__global__ __launch_bounds__(CTHREADS)
void chunk_nms_kernel(const float* __restrict__ scores,
                      const float2* __restrict__ ms_ws,
                      const float4* __restrict__ boxes_ws,
                      const unsigned short* __restrict__ ranks_ws,
                      uint64_t* __restrict__ ws_keys)
{
    __shared__ unsigned short sranks[A_N];    // 2.5 KB
    __shared__ float4         schunk[CH];     // 2 KB
    __shared__ uint32_t       scolp[8][64];   // per-wave 16-row column partials (2 KB)
    __shared__ unsigned char  sdead[CH];
    __shared__ float4         swbox[TOPK];    // winner boxes (cross-test)
    __shared__ unsigned short swidx[TOPK];    // winner anchor ids (rank order)
    __shared__ int            sW;

    const int blk = blockIdx.x;
    const int b   = blk / CF;
    const int c   = blk % CF + 1;
    const int t   = threadIdx.x;
    const int l   = t & 63;
    const int w   = t >> 6;                   // 0..7

    const unsigned short* const rsrc = ranks_ws + (size_t)blk * A_N;
    for (int i = t; i < A_N; i += CTHREADS) sranks[i] = rsrc[i];
    if (t == 0) sW = 0;
    __syncthreads();

    int W = 0;
    for (int cb = 0; cb < A_N; cb += CH) {
        if (sranks[cb] == 0xFFFF) break;      // sorted: rest invalid (uniform)

        // phase A: gather chunk boxes + init validity
        if (t < CH) {
            const unsigned short rk = sranks[cb + t];
            const bool v = (rk != 0xFFFF);
            schunk[t] = v ? boxes_ws[(size_t)b * A_N + rk]
                          : make_float4(-8.f, -8.f, -8.f, -8.f);
            sdead[t]  = v ? 0 : 1;
        }
        __syncthreads();

        const float4 box_lo = schunk[l];
        const float4 box_hi = schunk[64 + l];
        const float  al = box_area(box_lo);
        const float  ah = box_area(box_hi);

        // phase B1: cross-test vs prior winners, 4 helpers per box
        {
            const int bx = t >> 2, q = t & 3;
            const float4 bv = schunk[bx];
            const float  av = box_area(bv);
            int dead = 0;
            #pragma unroll 4
            for (int i = q; i < W; i += 4) {     // no early exit -> loads pipeline
                const float4 bw = swbox[i];
                dead |= iou_gt(bw, box_area(bw), bv, av) ? 1 : 0;
            }
            dead |= __shfl_xor(dead, 1, 64);
            dead |= __shfl_xor(dead, 2, 64);
            if (q == 0 && dead) sdead[bx] = 1;
        }
        __syncthreads();

        // phase B2: wave w builds rows [16w,16w+16) of all 128 columns, alive rows only
        {
            const int rbase = w * 16;
            uint32_t rm = (uint32_t)__ballot(l < 16 && !sdead[rbase + l]) & 0xFFFFu;
            uint32_t part = 0;
            while (rm) {                          // uniform per wave (ballot result)
                const int j = __ffs(rm) - 1; rm &= rm - 1;
                const int row = rbase + j;
                const float4 rowsrc = (row < 64) ? box_lo : box_hi;
                const float4 rbx = shfl_box(rowsrc, row & 63);
                const float  ra  = box_area(rbx);
                part |= (iou_gt(rbx, ra, box_lo, al) ? 1u : 0u) << j;            // col l
                part |= (iou_gt(rbx, ra, box_hi, ah) ? 0x10000u : 0u) << j;      // col 64+l
            }
            scolp[w][l] = part;
        }
        __syncthreads();

        // phase C: wave 0 assembles register kill-columns and resolves in rank order
        if (w == 0) {
            uint64_t c0 = 0, h0 = 0, c1 = 0, h1 = 0;
            #pragma unroll
            for (int ww = 0; ww < 4; ++ww) {
                const uint32_t plo = scolp[ww][l];       // rows [16ww,16ww+16)
                const uint32_t phi = scolp[ww + 4][l];   // rows [64+16ww, ...)
                c0 |= (uint64_t)(plo & 0xFFFFu) << (16 * ww);
                c1 |= (uint64_t)(plo >> 16)     << (16 * ww);
                h0 |= (uint64_t)(phi & 0xFFFFu) << (16 * ww);
                h1 |= (uint64_t)(phi >> 16)     << (16 * ww);
            }
            const unsigned short rk0 = sranks[cb + l];
            const unsigned short rk1 = sranks[cb + 64 + l];
            bool a0 = !sdead[l];
            bool a1 = !sdead[64 + l];
            int Wl = W;
            while (true) {
                const unsigned long long b0 = __ballot(a0);
                const unsigned long long b1 = __ballot(a1);
                if (!(b0 | b1)) break;
                const int f = b0 ? (__ffsll(b0) - 1) : (64 + __ffsll(b1) - 1);
                if (f < 64) {
                    if (l == f)      { swidx[Wl] = rk0; swbox[Wl] = box_lo; }
                } else {
                    if (l == f - 64) { swidx[Wl] = rk1; swbox[Wl] = box_hi; }
                }
                uint32_t k0, k1;
                if (f < 64) { k0 = (uint32_t)(c0 >> f) & 1;        k1 = (uint32_t)(c1 >> f) & 1; }
                else        { k0 = (uint32_t)(h0 >> (f - 64)) & 1; k1 = (uint32_t)(h1 >> (f - 64)) & 1; }
                a0 = a0 && !k0;                 // winner self-clears (IoU=1)
                a1 = a1 && !k1;
                if (++Wl >= TOPK) break;        // later winners can't reach output
            }
            if (l == 0) sW = Wl;
        }
        __syncthreads();
        W = sW;
        if (W >= TOPK) break;
    }

    // epilogue: reconstruct keys (bitwise == sort_kernel's) and write kept list
    const uint32_t  base = (uint32_t)(c - 1) * A_N;
    uint64_t* const out  = ws_keys + ((size_t)b * CF + (c - 1)) * TOPK;
    for (int k2 = t; k2 < TOPK; k2 += CTHREADS) {
        if (k2 < W) {
            const int a = swidx[k2];
            const float2 ms = ms_ws[(size_t)b * A_N + a];
            const float  sc = expf(scores[((size_t)b * A_N + a) * NC + c] - ms.x) / ms.y;
            out[k2] = ((uint64_t)(uint32_t)(~__float_as_uint(sc)) << 32)
                    | (uint64_t)(base + (uint32_t)a);
        } else {
            out[k2] = ~0ull;
        }
    }
}

// ---- mono fallback (R4 kernel, verified) for small ws ----
template <bool PREP>
__global__ __launch_bounds__(THREADS)
void nms_mono(const float* __restrict__ locs,
              const float* __restrict__ scores,
              const float* __restrict__ anchors,
              const float4* __restrict__ boxes_ws,
              const float2* __restrict__ ms_ws,
              uint64_t* __restrict__ ws_keys)
{
    __shared__ uint64_t      skeys[SORT_N];
    __shared__ float4        sbox[A_N];
    __shared__ float4        schunk[CH];
    __shared__ uint64_t      srow[CH][2];
    __shared__ float4        swbox[TOPK];
    __shared__ uint64_t      swkey[TOPK];
    __shared__ unsigned char sdead[CH];
    __shared__ int           sW;

    const int blk = blockIdx.x;
    const int b   = blk / CF;
    const int c   = blk % CF + 1;
    const int t   = threadIdx.x;
    const int l   = t & 63;
    const int w   = t >> 6;

    #pragma unroll
    for (int i = 0; i < A_N / THREADS; ++i) {
        const int a = t + i * THREADS;
        float4 v; float m, sum;
        if (PREP) {
            v = boxes_ws[b * A_N + a];
            const float2 ms = ms_ws[b * A_N + a];
            m = ms.x; sum = ms.y;
        } else {
            v = decode_box(((const float4*)locs)[(size_t)b * A_N + a],
                           ((const float4*)anchors)[a]);
            const float* sp = scores + ((size_t)b * A_N + a) * NC;
            m = sp[0];
            #pragma unroll
            for (int k = 1; k < NC; ++k) m = fmaxf(m, sp[k]);
            sum = 0.0f;
            #pragma unroll
            for (int k = 0; k < NC; ++k) sum += expf(sp[k] - m);
        }
        sbox[a] = v;
        const float sl = scores[((size_t)b * A_N + a) * NC + c];
        const float sc = expf(sl - m) / sum;
        skeys[a] = (sc > 0.01f) ? pack_key(sc, (uint32_t)a) : ~0ull;
    }
    for (int i = A_N + t; i < SORT_N; i += THREADS) skeys[i] = ~0ull;
    if (t == 0) sW = 0;
    __syncthreads();

    uint64_t k[8];
    #pragma unroll
    for (int r = 0; r < 8; ++r) k[r] = skeys[(w << 9) + (r << 6) + l];
    for (int kk = 2; kk <= SORT_N; kk <<= 1) {
        for (int j = kk >> 1; j; j >>= 1) {
            if (j >= 512) {
                __syncthreads();
                #pragma unroll
                for (int r = 0; r < 8; ++r) skeys[(w << 9) + (r << 6) + l] = k[r];
                __syncthreads();
                #pragma unroll
                for (int r = 0; r < 8; ++r) {
                    const int e = (w << 9) + (r << 6) + l;
                    const uint64_t o = skeys[e ^ j];
                    const bool keep_min = (((e & j) == 0) == ((e & kk) == 0));
                    const uint64_t mn = k[r] < o ? k[r] : o;
                    const uint64_t mx = k[r] < o ? o : k[r];
                    k[r] = keep_min ? mn : mx;
                }
            } else if (j >= 64) {
                const int rb = j >> 6;
                #pragma unroll
                for (int r = 0; r < 8; ++r) {
                    if ((r & rb) == 0) {
                        const int p = r | rb;
                        const int e = (w << 9) + (r << 6) + l;
                        const bool up = ((e & kk) == 0);
                        const uint64_t x = k[r], y = k[p];
                        const uint64_t mn = x < y ? x : y;
                        const uint64_t mx = x < y ? y : x;
                        k[r] = up ? mn : mx;
                        k[p] = up ? mx : mn;
                    }
                }
            } else {
                #pragma unroll
                for (int r = 0; r < 8; ++r) {
                    const uint64_t o = (uint64_t)__shfl_xor((unsigned long long)k[r], j, 64);
                    const int e = (w << 9) + (r << 6) + l;
                    const bool keep_min = (((e & j) == 0) == ((e & kk) == 0));
                    const uint64_t mn = k[r] < o ? k[r] : o;
                    const uint64_t mx = k[r] < o ? o : k[r];
                    k[r] = keep_min ? mn : mx;
                }
            }
        }
    }
    __syncthreads();
    #pragma unroll
    for (int r = 0; r < 8; ++r) skeys[(w << 9) + (r << 6) + l] = k[r];
    __syncthreads();

    int W = 0;
    for (int cb = 0; cb < SORT_N; cb += CH) {
        if (skeys[cb] == ~0ull) break;
        if (t < CH) {
            const uint64_t kc = skeys[cb + t];
            const bool v = (kc != ~0ull);
            schunk[t] = v ? sbox[(uint32_t)kc] : make_float4(-8.f, -8.f, -8.f, -8.f);
            sdead[t]  = v ? 0 : 1;
        }
        __syncthreads();
        const float4 cb0 = schunk[l];
        const float4 cb1 = schunk[64 + l];
        const float  ca0 = box_area(cb0);
        const float  ca1 = box_area(cb1);
        for (int r = w * 32; r < w * 32 + 32; ++r) {
            const float4 rbx = schunk[r];
            const float  ra  = box_area(rbx);
            const uint64_t m0 = __ballot(iou_gt(rbx, ra, cb0, ca0));
            const uint64_t m1 = __ballot(iou_gt(rbx, ra, cb1, ca1));
            if (l == 0) { srow[r][0] = m0; srow[r][1] = m1; }
        }
        {
            const int jj = t >> 1, h = t & 1;
            const float4 bj = schunk[jj];
            const float  aj = box_area(bj);
            int sup = 0;
            for (int w2 = h; w2 < W; w2 += 2) {
                const float4 bw = swbox[w2];
                if (iou_gt(bw, box_area(bw), bj, aj)) { sup = 1; break; }
            }
            sup |= __shfl_xor(sup, 1, 64);
            if (h == 0 && sup) sdead[jj] = 1;
        }
        __syncthreads();
        if (t < 64) {
            bool al0 = !sdead[t];
            bool al1 = !sdead[64 + t];
            int Wl = W;
            while (true) {
                const unsigned long long bal0 = __ballot(al0);
                const unsigned long long bal1 = __ballot(al1);
                if (!(bal0 | bal1)) break;
                const int f = bal0 ? (__ffsll(bal0) - 1) : (64 + __ffsll(bal1) - 1);
                if (t == 0) { swkey[Wl] = skeys[cb + f]; swbox[Wl] = schunk[f]; }
                const uint64_t r0 = srow[f][0];
                const uint64_t r1 = srow[f][1];
                al0 = al0 && !((r0 >> t) & 1);
                al1 = al1 && !((r1 >> t) & 1);
                if (++Wl >= TOPK) break;
            }
            if (t == 0) sW = Wl;
        }
        __syncthreads();
        W = sW;
        if (W >= TOPK) break;
    }

    const uint32_t  base = (uint32_t)(c - 1) * A_N;
    uint64_t* const out  = ws_keys + ((size_t)b * CF + (c - 1)) * TOPK;
    for (int kx = t; kx < TOPK; kx += THREADS) {
        if (kx < W) {
            const uint64_t kk2 = swkey[kx];
            out[kx] = (kk2 & 0xFFFFFFFF00000000ull) | (uint64_t)(base + (uint32_t)kk2);
        } else {
            out[kx] = ~0ull;
        }
    }
}

// ---- merge: per batch top-200 of 20 sorted lists (R2..R6-verified) ----
__global__ __launch_bounds__(THREADS)
void merge_kernel(const float* __restrict__ locs,
                  const float* __restrict__ anchors,
                  const uint64_t* __restrict__ ws_keys,
                  float* __restrict__ out)
{
    __shared__ uint64_t Abuf[20][256];
    __shared__ uint64_t Bbuf[10][256];

    const int b = blockIdx.x;
    const int t = threadIdx.x;
    const uint64_t* const in = ws_keys + (size_t)b * CF * TOPK;

    for (int e = t; e < CF * 256; e += THREADS) {
        const int c = e >> 8, i = e & 255;
        Abuf[c][i] = (i < TOPK) ? in[c * TOPK + i] : ~0ull;
    }

    uint64_t (*src)[256] = Abuf;
    uint64_t (*dst)[256] = Bbuf;
    int n = CF;
    while (n > 1) {
        const int  nm    = n >> 1;
        const bool carry = (n & 1) != 0;
        __syncthreads();
        for (int e = t; e < nm * 256; e += THREADS) {
            const int mm = e >> 8, i = e & 255;
            const uint64_t x = src[2 * mm][i];
            const uint64_t y = src[2 * mm + 1][255 - i];
            dst[mm][i] = x < y ? x : y;
        }
        if (carry)
            for (int i = t; i < 256; i += THREADS) dst[nm][i] = src[n - 1][i];
        for (int j = 128; j; j >>= 1) {
            __syncthreads();
            for (int pp = t; pp < nm * 128; pp += THREADS) {
                const int mm = pp >> 7, qq = pp & 127;
                const int i  = ((qq & ~(j - 1)) << 1) | (qq & (j - 1));
                const uint64_t x = dst[mm][i], y = dst[mm][i + j];
                if (y < x) { dst[mm][i] = y; dst[mm][i + j] = x; }
            }
        }
        uint64_t (*tmp)[256] = src; src = dst; dst = tmp;
        n = nm + (carry ? 1 : 0);
    }
    __syncthreads();

    if (t < TOPK) {
        const uint64_t k = src[0][t];
        float* const boxes_out  = out;
        float* const labels_out = out + (size_t)B_N * TOPK * 4;
        float* const scores_out = out + (size_t)B_N * TOPK * 5;
        const size_t s = (size_t)b * TOPK + t;
        if (k == ~0ull) {
            boxes_out[s * 4 + 0] = 0.0f;
            boxes_out[s * 4 + 1] = 0.0f;
            boxes_out[s * 4 + 2] = 0.0f;
            boxes_out[s * 4 + 3] = 0.0f;
            labels_out[s] = 0.0f;
            scores_out[s] = 0.0f;
        } else {
            const uint32_t flat = (uint32_t)k;
            const int cls = flat / A_N;
            const int a   = flat - cls * A_N;
            const float sc = __uint_as_float(~(uint32_t)(k >> 32));
            const float4 v = decode_box(((const float4*)locs)[(size_t)b * A_N + a],
                                        ((const float4*)anchors)[a]);
            boxes_out[s * 4 + 0] = v.x;
            boxes_out[s * 4 + 1] = v.y;
            boxes_out[s * 4 + 2] = v.z;
            boxes_out[s * 4 + 3] = v.w;
            labels_out[s] = (float)(cls + 1);
            scores_out[s] = sc;
        }
    }
}

extern "C" void kernel_launch(void* const* d_in, const int* in_sizes, int n_in,
                              void* d_out, int out_size, void* d_ws, size_t ws_size,
                              hipStream_t stream) {
    const float* locs    = (const float*)d_in[0];
    const float* scores  = (const float*)d_in[1];
    const float* anchors = (const float*)d_in[2];
    uint64_t*       ws_keys  = (uint64_t*)d_ws;
    float4*         boxes_ws = (float4*)((char*)d_ws + BOX_OFF);
    float2*         ms_ws    = (float2*)((char*)d_ws + MS_OFF);
    unsigned short* ranks_ws = (unsigned short*)((char*)d_ws + RANKS_OFF);
    float*          outp     = (float*)d_out;

    if (ws_size >= WS_A_BYTES) {
        hipLaunchKernelGGL(prep_kernel, dim3((B_N * A_N + THREADS - 1) / THREADS),
                           dim3(THREADS), 0, stream, locs, scores, anchors, boxes_ws, ms_ws);
        hipLaunchKernelGGL(sort_kernel, dim3(B_N * CF), dim3(THREADS), 0, stream,
                           scores, ms_ws, ranks_ws);
        hipLaunchKernelGGL(chunk_nms_kernel, dim3(B_N * CF), dim3(CTHREADS), 0, stream,
                           scores, ms_ws, boxes_ws, ranks_ws, ws_keys);
    } else if (ws_size >= WS_B_BYTES) {
        hipLaunchKernelGGL(prep_kernel, dim3((B_N * A_N + THREADS - 1) / THREADS),
                           dim3(THREADS), 0, stream, locs, scores, anchors, boxes_ws, ms_ws);
        hipLaunchKernelGGL((nms_mono<true>), dim3(B_N * CF), dim3(THREADS), 0, stream,
                           locs, scores, anchors, boxes_ws, ms_ws, ws_keys);
    } else {
        hipLaunchKernelGGL((nms_mono<false>), dim3(B_N * CF), dim3(THREADS), 0, stream,
                           locs, scores, anchors, boxes_ws, ms_ws, ws_keys);
    }
    hipLaunchKernelGGL(merge_kernel, dim3(B_N), dim3(THREADS), 0, stream,
                       locs, anchors, ws_keys, outp);
}

// Round 8
// 180.384 us; speedup vs baseline: 1.5943x; 1.0427x over previous
//
#include <hip/hip_runtime.h>
#include <stdint.h>

// DetectionBaseline: SSD post-process. R8: chunk_nms resolve de-ballot-ified —
//  - resolve: alive mask held as uniform scalars; kill rows in wave-0 VGPRs;
//    per-winner chain = ctz + 4x v_readlane + scalar andn (no cross-lane ballot)
//  - 3 phases/chunk (direct global box loads replace the LDS gather phase)
// prep / sort / merge / mono-fallback unchanged (verified absmax 0.0 R4-R7).

#define A_N     1280
#define CF      20
#define NC      21
#define B_N     16
#define TOPK    200
#define THREADS 256
#define CTHREADS 512
#define SORT_N  2048
#define CH      128

// ws layout (bytes)
#define KEYS_BYTES   (B_N * CF * TOPK * 8)                 // 512000 kept-key lists
#define BOX_OFF      KEYS_BYTES                             // float4 [16*1280] = 327680
#define MS_OFF       (BOX_OFF + B_N * A_N * 16)             // float2 [16*1280] = 163840
#define RANKS_OFF    (MS_OFF + B_N * A_N * 8)               // u16 [320*1280]   = 819200
#define WS_B_BYTES   RANKS_OFF                              // 1003520 (mono-prep tier)
#define WS_A_BYTES   (RANKS_OFF + (size_t)B_N * CF * A_N * 2)  // 1822720 (split tier)

static __device__ __forceinline__ uint64_t pack_key(float sc, uint32_t idx) {
    // softmax scores positive -> float bits monotone. ~bits => ascending key = descending
    // score; low 32 bits = index => ties break toward smaller index (stable argsort / top_k).
    return ((uint64_t)(uint32_t)(~__float_as_uint(sc)) << 32) | (uint64_t)idx;
}

static __device__ __forceinline__ float box_area(const float4 v) {
    return (v.z - v.x) * (v.w - v.y);
}

static __device__ __forceinline__ bool iou_gt(const float4 a, const float aarea,
                                              const float4 b, const float barea) {
    // ref-exact: inter/(area_row + area_col - inter) > 0.45
    const float lx = fmaxf(a.x, b.x);
    const float ly = fmaxf(a.y, b.y);
    const float rx = fminf(a.z, b.z);
    const float ry = fminf(a.w, b.w);
    const float wx = fmaxf(rx - lx, 0.0f);
    const float wy = fmaxf(ry - ly, 0.0f);
    const float inter = wx * wy;
    const float uni   = aarea + barea - inter;
    return inter / uni > 0.45f;
}

static __device__ __forceinline__ float4 decode_box(const float4 lc, const float4 an) {
    const float cx = lc.x * an.z / 10.0f + an.x;
    const float cy = lc.y * an.w / 10.0f + an.y;
    const float w  = expf(lc.z / 5.0f) * an.z;
    const float h  = expf(lc.w / 5.0f) * an.w;
    float4 v;
    v.x = cx - w / 2.0f; v.y = cy - h / 2.0f;
    v.z = cx + w / 2.0f; v.w = cy + h / 2.0f;
    return v;
}

static __device__ __forceinline__ float4 shfl_box(const float4 v, int lane) {
    float4 r;
    r.x = __shfl(v.x, lane, 64);
    r.y = __shfl(v.y, lane, 64);
    r.z = __shfl(v.z, lane, 64);
    r.w = __shfl(v.w, lane, 64);
    return r;
}

static __device__ __forceinline__ uint64_t readlane_u64(uint64_t v, int lane) {
    const uint32_t lo = (uint32_t)__builtin_amdgcn_readlane((int)(uint32_t)v, lane);
    const uint32_t hi = (uint32_t)__builtin_amdgcn_readlane((int)(uint32_t)(v >> 32), lane);
    return ((uint64_t)hi << 32) | lo;
}

// ---- prep: per (b,a) decoded box + softmax (max, sum) ----
__global__ __launch_bounds__(THREADS)
void prep_kernel(const float* __restrict__ locs,
                 const float* __restrict__ scores,
                 const float* __restrict__ anchors,
                 float4* __restrict__ boxes_ws,
                 float2* __restrict__ ms_ws)
{
    const int g = blockIdx.x * THREADS + threadIdx.x;
    if (g >= B_N * A_N) return;
    const int a = g % A_N;
    boxes_ws[g] = decode_box(((const float4*)locs)[g], ((const float4*)anchors)[a]);
    const float* sp = scores + (size_t)g * NC;
    float m = sp[0];
    #pragma unroll
    for (int k = 1; k < NC; ++k) m = fmaxf(m, sp[k]);
    float sum = 0.0f;
    #pragma unroll
    for (int k = 0; k < NC; ++k) sum += expf(sp[k] - m);
    ms_ws[g] = make_float2(m, sum);
}

// ---- sort: per (b,c) build keys, register bitonic sort, emit u16 rank list ----
__global__ __launch_bounds__(THREADS)
void sort_kernel(const float* __restrict__ scores,
                 const float2* __restrict__ ms_ws,
                 unsigned short* __restrict__ ranks_ws)
{
    __shared__ uint64_t skeys[SORT_N];   // 16 KB

    const int blk = blockIdx.x;
    const int b   = blk / CF;
    const int c   = blk % CF + 1;
    const int t   = threadIdx.x;
    const int l   = t & 63;
    const int w   = t >> 6;

    #pragma unroll
    for (int i = 0; i < A_N / THREADS; ++i) {
        const int a = t + i * THREADS;
        const float2 ms = ms_ws[b * A_N + a];
        const float  sl = scores[((size_t)b * A_N + a) * NC + c];
        const float  sc = expf(sl - ms.x) / ms.y;          // ref-exact softmax value
        skeys[a] = (sc > 0.01f) ? pack_key(sc, (uint32_t)a) : ~0ull;
    }
    for (int i = A_N + t; i < SORT_N; i += THREADS) skeys[i] = ~0ull;
    __syncthreads();

    // register/wave bitonic sort, element e = w*512 + r*64 + l (R4..R7-verified)
    uint64_t k[8];
    #pragma unroll
    for (int r = 0; r < 8; ++r) k[r] = skeys[(w << 9) + (r << 6) + l];

    for (int kk = 2; kk <= SORT_N; kk <<= 1) {
        for (int j = kk >> 1; j; j >>= 1) {
            if (j >= 512) {
                __syncthreads();
                #pragma unroll
                for (int r = 0; r < 8; ++r) skeys[(w << 9) + (r << 6) + l] = k[r];
                __syncthreads();
                #pragma unroll
                for (int r = 0; r < 8; ++r) {
                    const int e = (w << 9) + (r << 6) + l;
                    const uint64_t o = skeys[e ^ j];
                    const bool keep_min = (((e & j) == 0) == ((e & kk) == 0));
                    const uint64_t mn = k[r] < o ? k[r] : o;
                    const uint64_t mx = k[r] < o ? o : k[r];
                    k[r] = keep_min ? mn : mx;
                }
            } else if (j >= 64) {
                const int rb = j >> 6;
                #pragma unroll
                for (int r = 0; r < 8; ++r) {
                    if ((r & rb) == 0) {
                        const int p = r | rb;
                        const int e = (w << 9) + (r << 6) + l;
                        const bool up = ((e & kk) == 0);
                        const uint64_t x = k[r], y = k[p];
                        const uint64_t mn = x < y ? x : y;
                        const uint64_t mx = x < y ? y : x;
                        k[r] = up ? mn : mx;
                        k[p] = up ? mx : mn;
                    }
                }
            } else {
                #pragma unroll
                for (int r = 0; r < 8; ++r) {
                    const uint64_t o = (uint64_t)__shfl_xor((unsigned long long)k[r], j, 64);
                    const int e = (w << 9) + (r << 6) + l;
                    const bool keep_min = (((e & j) == 0) == ((e & kk) == 0));
                    const uint64_t mn = k[r] < o ? k[r] : o;
                    const uint64_t mx = k[r] < o ? o : k[r];
                    k[r] = keep_min ? mn : mx;
                }
            }
        }
    }
    // valid candidates <= 1280 -> ranks >= 1280 all-invalid: store first 1280 only
    unsigned short* const dst = ranks_ws + (size_t)blk * A_N;
    #pragma unroll
    for (int r = 0; r < 8; ++r) {
        const int e = (w << 9) + (r << 6) + l;
        if (e < A_N)
            dst[e] = (k[r] == ~0ull) ? (unsigned short)0xFFFF
                                     : (unsigned short)(k[r] & 0xFFFF);
    }
}

// ---- chunk_nms (512 threads): 3 phases/chunk, scalar readlane resolve ----
__global__ __launch_bounds__(CTHREADS)
void chunk_nms_kernel(const float* __restrict__ scores,
                      const float2* __restrict__ ms_ws,
                      const float4* __restrict__ boxes_ws,
                      const unsigned short* __restrict__ ranks_ws,
                      uint64_t* __restrict__ ws_keys)
{
    __shared__ unsigned short sranks[A_N];    // 2.5 KB (stable after prologue)
    __shared__ uint64_t       srow[CH][2];    // kill rows, 128 bits each (2 KB)
    __shared__ unsigned char  sdead[CH];
    __shared__ float4         swbox[TOPK];    // winner boxes (cross-test)
    __shared__ float          swarea[TOPK];   // winner areas
    __shared__ unsigned short swidx[TOPK];    // winner anchor ids (rank order)
    __shared__ int            sW;

    const int blk = blockIdx.x;
    const int b   = blk / CF;
    const int c   = blk % CF + 1;
    const int t   = threadIdx.x;
    const int l   = t & 63;
    const int w   = t >> 6;                   // 0..7

    const unsigned short* const rsrc = ranks_ws + (size_t)blk * A_N;
    const float4* const bbase = boxes_ws + (size_t)b * A_N;
    for (int i = t; i < A_N; i += CTHREADS) sranks[i] = rsrc[i];
    if (t == 0) sW = 0;
    __syncthreads();

    int W = 0;
    for (int cb = 0; cb < A_N; cb += CH) {
        if (sranks[cb] == 0xFFFF) break;      // sorted: rest invalid (uniform)

        // column boxes for this chunk: lane l holds cols l and 64+l (L2-hot loads)
        const unsigned short rk0 = sranks[cb + l];
        const unsigned short rk1 = sranks[cb + 64 + l];
        const float4 box_lo = (rk0 != 0xFFFF) ? bbase[rk0] : make_float4(-8.f, -8.f, -8.f, -8.f);
        const float4 box_hi = (rk1 != 0xFFFF) ? bbase[rk1] : make_float4(-8.f, -8.f, -8.f, -8.f);
        const float  al = box_area(box_lo);
        const float  ah = box_area(box_hi);

        // P1: cross-test vs prior winners, 4 helpers per box (direct global box load)
        {
            const int bx = t >> 2, q = t & 3;
            const unsigned short rkx = sranks[cb + bx];
            const bool valid = (rkx != 0xFFFF);
            const float4 bv = valid ? bbase[rkx] : make_float4(-8.f, -8.f, -8.f, -8.f);
            const float  av = box_area(bv);
            int dead = valid ? 0 : 1;
            #pragma unroll 4
            for (int i = q; i < W; i += 4) {     // no early exit -> loads pipeline
                dead |= iou_gt(swbox[i], swarea[i], bv, av) ? 1 : 0;
            }
            dead |= __shfl_xor(dead, 1, 64);
            dead |= __shfl_xor(dead, 2, 64);
            if (q == 0) sdead[bx] = (unsigned char)dead;
        }
        __syncthreads();

        // P2: sparse alive-row kill-matrix build; wave w owns rows [16w,16w+16)
        {
            const int rbase = w * 16;
            uint32_t rm = (uint32_t)__ballot(l < 16 && !sdead[rbase + l]) & 0xFFFFu;
            while (rm) {                          // uniform per wave (ballot result)
                const int j = __ffs(rm) - 1; rm &= rm - 1;
                const int row = rbase + j;
                const float4 rowsrc = (row < 64) ? box_lo : box_hi;
                const float4 rbx = shfl_box(rowsrc, row & 63);
                const float  ra  = box_area(rbx);
                const uint64_t m0 = __ballot(iou_gt(rbx, ra, box_lo, al));
                const uint64_t m1 = __ballot(iou_gt(rbx, ra, box_hi, ah));
                if (l == 0) { srow[row][0] = m0; srow[row][1] = m1; }
            }
        }
        __syncthreads();

        // P3: wave-0 scalar resolve — alive as uniform scalars, rows in VGPRs,
        //     per-winner chain = ctz + readlane + andn (no ballots)
        if (w == 0) {
            const uint64_t r0lo = srow[l][0];        // row l
            const uint64_t r0hi = srow[l][1];
            const uint64_t r1lo = srow[64 + l][0];   // row 64+l
            const uint64_t r1hi = srow[64 + l][1];
            uint64_t alive0 = __ballot(sdead[l] == 0);        // one-time
            uint64_t alive1 = __ballot(sdead[64 + l] == 0);
            int Wl = W;
            while ((alive0 | alive1) && Wl < TOPK) {
                const int f = alive0 ? __builtin_ctzll(alive0)
                                     : 64 + __builtin_ctzll(alive1);
                if (f < 64) {
                    if (l == f)      { swidx[Wl] = rk0; swbox[Wl] = box_lo; swarea[Wl] = al; }
                } else {
                    if (l == f - 64) { swidx[Wl] = rk1; swbox[Wl] = box_hi; swarea[Wl] = ah; }
                }
                uint64_t klo, khi;
                if (f < 64) { klo = readlane_u64(r0lo, f);      khi = readlane_u64(r0hi, f); }
                else        { klo = readlane_u64(r1lo, f - 64); khi = readlane_u64(r1hi, f - 64); }
                alive0 &= ~klo;                  // winner self-clears (row bit f = 1)
                alive1 &= ~khi;
                ++Wl;
            }
            if (l == 0) sW = Wl;
        }
        __syncthreads();
        W = sW;
        if (W >= TOPK) break;
    }

    // epilogue: reconstruct keys (bitwise == sort_kernel's) and write kept list
    const uint32_t  base = (uint32_t)(c - 1) * A_N;
    uint64_t* const out  = ws_keys + ((size_t)b * CF + (c - 1)) * TOPK;
    for (int k2 = t; k2 < TOPK; k2 += CTHREADS) {
        if (k2 < W) {
            const int a = swidx[k2];
            const float2 ms = ms_ws[(size_t)b * A_N + a];
            const float  sc = expf(scores[((size_t)b * A_N + a) * NC + c] - ms.x) / ms.y;
            out[k2] = ((uint64_t)(uint32_t)(~__float_as_uint(sc)) << 32)
                    | (uint64_t)(base + (uint32_t)a);
        } else {
            out[k2] = ~0ull;
        }
    }
}

// ---- mono fallback (R4 kernel, verified) for small ws ----
template <bool PREP>
__global__ __launch_bounds__(THREADS)
void nms_mono(const float* __restrict__ locs,
              const float* __restrict__ scores,
              const float* __restrict__ anchors,
              const float4* __restrict__ boxes_ws,
              const float2* __restrict__ ms_ws,
              uint64_t* __restrict__ ws_keys)
{
    __shared__ uint64_t      skeys[SORT_N];
    __shared__ float4        sbox[A_N];
    __shared__ float4        schunk[CH];
    __shared__ uint64_t      srow[CH][2];
    __shared__ float4        swbox[TOPK];
    __shared__ uint64_t      swkey[TOPK];
    __shared__ unsigned char sdead[CH];
    __shared__ int           sW;

    const int blk = blockIdx.x;
    const int b   = blk / CF;
    const int c   = blk % CF + 1;
    const int t   = threadIdx.x;
    const int l   = t & 63;
    const int w   = t >> 6;

    #pragma unroll
    for (int i = 0; i < A_N / THREADS; ++i) {
        const int a = t + i * THREADS;
        float4 v; float m, sum;
        if (PREP) {
            v = boxes_ws[b * A_N + a];
            const float2 ms = ms_ws[b * A_N + a];
            m = ms.x; sum = ms.y;
        } else {
            v = decode_box(((const float4*)locs)[(size_t)b * A_N + a],
                           ((const float4*)anchors)[a]);
            const float* sp = scores + ((size_t)b * A_N + a) * NC;
            m = sp[0];
            #pragma unroll
            for (int k = 1; k < NC; ++k) m = fmaxf(m, sp[k]);
            sum = 0.0f;
            #pragma unroll
            for (int k = 0; k < NC; ++k) sum += expf(sp[k] - m);
        }
        sbox[a] = v;
        const float sl = scores[((size_t)b * A_N + a) * NC + c];
        const float sc = expf(sl - m) / sum;
        skeys[a] = (sc > 0.01f) ? pack_key(sc, (uint32_t)a) : ~0ull;
    }
    for (int i = A_N + t; i < SORT_N; i += THREADS) skeys[i] = ~0ull;
    if (t == 0) sW = 0;
    __syncthreads();

    uint64_t k[8];
    #pragma unroll
    for (int r = 0; r < 8; ++r) k[r] = skeys[(w << 9) + (r << 6) + l];
    for (int kk = 2; kk <= SORT_N; kk <<= 1) {
        for (int j = kk >> 1; j; j >>= 1) {
            if (j >= 512) {
                __syncthreads();
                #pragma unroll
                for (int r = 0; r < 8; ++r) skeys[(w << 9) + (r << 6) + l] = k[r];
                __syncthreads();
                #pragma unroll
                for (int r = 0; r < 8; ++r) {
                    const int e = (w << 9) + (r << 6) + l;
                    const uint64_t o = skeys[e ^ j];
                    const bool keep_min = (((e & j) == 0) == ((e & kk) == 0));
                    const uint64_t mn = k[r] < o ? k[r] : o;
                    const uint64_t mx = k[r] < o ? o : k[r];
                    k[r] = keep_min ? mn : mx;
                }
            } else if (j >= 64) {
                const int rb = j >> 6;
                #pragma unroll
                for (int r = 0; r < 8; ++r) {
                    if ((r & rb) == 0) {
                        const int p = r | rb;
                        const int e = (w << 9) + (r << 6) + l;
                        const bool up = ((e & kk) == 0);
                        const uint64_t x = k[r], y = k[p];
                        const uint64_t mn = x < y ? x : y;
                        const uint64_t mx = x < y ? y : x;
                        k[r] = up ? mn : mx;
                        k[p] = up ? mx : mn;
                    }
                }
            } else {
                #pragma unroll
                for (int r = 0; r < 8; ++r) {
                    const uint64_t o = (uint64_t)__shfl_xor((unsigned long long)k[r], j, 64);
                    const int e = (w << 9) + (r << 6) + l;
                    const bool keep_min = (((e & j) == 0) == ((e & kk) == 0));
                    const uint64_t mn = k[r] < o ? k[r] : o;
                    const uint64_t mx = k[r] < o ? o : k[r];
                    k[r] = keep_min ? mn : mx;
                }
            }
        }
    }
    __syncthreads();
    #pragma unroll
    for (int r = 0; r < 8; ++r) skeys[(w << 9) + (r << 6) + l] = k[r];
    __syncthreads();

    int W = 0;
    for (int cb = 0; cb < SORT_N; cb += CH) {
        if (skeys[cb] == ~0ull) break;
        if (t < CH) {
            const uint64_t kc = skeys[cb + t];
            const bool v = (kc != ~0ull);
            schunk[t] = v ? sbox[(uint32_t)kc] : make_float4(-8.f, -8.f, -8.f, -8.f);
            sdead[t]  = v ? 0 : 1;
        }
        __syncthreads();
        const float4 cb0 = schunk[l];
        const float4 cb1 = schunk[64 + l];
        const float  ca0 = box_area(cb0);
        const float  ca1 = box_area(cb1);
        for (int r = w * 32; r < w * 32 + 32; ++r) {
            const float4 rbx = schunk[r];
            const float  ra  = box_area(rbx);
            const uint64_t m0 = __ballot(iou_gt(rbx, ra, cb0, ca0));
            const uint64_t m1 = __ballot(iou_gt(rbx, ra, cb1, ca1));
            if (l == 0) { srow[r][0] = m0; srow[r][1] = m1; }
        }
        {
            const int jj = t >> 1, h = t & 1;
            const float4 bj = schunk[jj];
            const float  aj = box_area(bj);
            int sup = 0;
            for (int w2 = h; w2 < W; w2 += 2) {
                const float4 bw = swbox[w2];
                if (iou_gt(bw, box_area(bw), bj, aj)) { sup = 1; break; }
            }
            sup |= __shfl_xor(sup, 1, 64);
            if (h == 0 && sup) sdead[jj] = 1;
        }
        __syncthreads();
        if (t < 64) {
            bool al0 = !sdead[t];
            bool al1 = !sdead[64 + t];
            int Wl = W;
            while (true) {
                const unsigned long long bal0 = __ballot(al0);
                const unsigned long long bal1 = __ballot(al1);
                if (!(bal0 | bal1)) break;
                const int f = bal0 ? (__ffsll(bal0) - 1) : (64 + __ffsll(bal1) - 1);
                if (t == 0) { swkey[Wl] = skeys[cb + f]; swbox[Wl] = schunk[f]; }
                const uint64_t r0 = srow[f][0];
                const uint64_t r1 = srow[f][1];
                al0 = al0 && !((r0 >> t) & 1);
                al1 = al1 && !((r1 >> t) & 1);
                if (++Wl >= TOPK) break;
            }
            if (t == 0) sW = Wl;
        }
        __syncthreads();
        W = sW;
        if (W >= TOPK) break;
    }

    const uint32_t  base = (uint32_t)(c - 1) * A_N;
    uint64_t* const out  = ws_keys + ((size_t)b * CF + (c - 1)) * TOPK;
    for (int kx = t; kx < TOPK; kx += THREADS) {
        if (kx < W) {
            const uint64_t kk2 = swkey[kx];
            out[kx] = (kk2 & 0xFFFFFFFF00000000ull) | (uint64_t)(base + (uint32_t)kk2);
        } else {
            out[kx] = ~0ull;
        }
    }
}

// ---- merge: per batch top-200 of 20 sorted lists (R2..R7-verified) ----
__global__ __launch_bounds__(THREADS)
void merge_kernel(const float* __restrict__ locs,
                  const float* __restrict__ anchors,
                  const uint64_t* __restrict__ ws_keys,
                  float* __restrict__ out)
{
    __shared__ uint64_t Abuf[20][256];
    __shared__ uint64_t Bbuf[10][256];

    const int b = blockIdx.x;
    const int t = threadIdx.x;
    const uint64_t* const in = ws_keys + (size_t)b * CF * TOPK;

    for (int e = t; e < CF * 256; e += THREADS) {
        const int c = e >> 8, i = e & 255;
        Abuf[c][i] = (i < TOPK) ? in[c * TOPK + i] : ~0ull;
    }

    uint64_t (*src)[256] = Abuf;
    uint64_t (*dst)[256] = Bbuf;
    int n = CF;
    while (n > 1) {
        const int  nm    = n >> 1;
        const bool carry = (n & 1) != 0;
        __syncthreads();
        for (int e = t; e < nm * 256; e += THREADS) {
            const int mm = e >> 8, i = e & 255;
            const uint64_t x = src[2 * mm][i];
            const uint64_t y = src[2 * mm + 1][255 - i];
            dst[mm][i] = x < y ? x : y;
        }
        if (carry)
            for (int i = t; i < 256; i += THREADS) dst[nm][i] = src[n - 1][i];
        for (int j = 128; j; j >>= 1) {
            __syncthreads();
            for (int pp = t; pp < nm * 128; pp += THREADS) {
                const int mm = pp >> 7, qq = pp & 127;
                const int i  = ((qq & ~(j - 1)) << 1) | (qq & (j - 1));
                const uint64_t x = dst[mm][i], y = dst[mm][i + j];
                if (y < x) { dst[mm][i] = y; dst[mm][i + j] = x; }
            }
        }
        uint64_t (*tmp)[256] = src; src = dst; dst = tmp;
        n = nm + (carry ? 1 : 0);
    }
    __syncthreads();

    if (t < TOPK) {
        const uint64_t k = src[0][t];
        float* const boxes_out  = out;
        float* const labels_out = out + (size_t)B_N * TOPK * 4;
        float* const scores_out = out + (size_t)B_N * TOPK * 5;
        const size_t s = (size_t)b * TOPK + t;
        if (k == ~0ull) {
            boxes_out[s * 4 + 0] = 0.0f;
            boxes_out[s * 4 + 1] = 0.0f;
            boxes_out[s * 4 + 2] = 0.0f;
            boxes_out[s * 4 + 3] = 0.0f;
            labels_out[s] = 0.0f;
            scores_out[s] = 0.0f;
        } else {
            const uint32_t flat = (uint32_t)k;
            const int cls = flat / A_N;
            const int a   = flat - cls * A_N;
            const float sc = __uint_as_float(~(uint32_t)(k >> 32));
            const float4 v = decode_box(((const float4*)locs)[(size_t)b * A_N + a],
                                        ((const float4*)anchors)[a]);
            boxes_out[s * 4 + 0] = v.x;
            boxes_out[s * 4 + 1] = v.y;
            boxes_out[s * 4 + 2] = v.z;
            boxes_out[s * 4 + 3] = v.w;
            labels_out[s] = (float)(cls + 1);
            scores_out[s] = sc;
        }
    }
}

extern "C" void kernel_launch(void* const* d_in, const int* in_sizes, int n_in,
                              void* d_out, int out_size, void* d_ws, size_t ws_size,
                              hipStream_t stream) {
    const float* locs    = (const float*)d_in[0];
    const float* scores  = (const float*)d_in[1];
    const float* anchors = (const float*)d_in[2];
    uint64_t*       ws_keys  = (uint64_t*)d_ws;
    float4*         boxes_ws = (float4*)((char*)d_ws + BOX_OFF);
    float2*         ms_ws    = (float2*)((char*)d_ws + MS_OFF);
    unsigned short* ranks_ws = (unsigned short*)((char*)d_ws + RANKS_OFF);
    float*          outp     = (float*)d_out;

    if (ws_size >= WS_A_BYTES) {
        hipLaunchKernelGGL(prep_kernel, dim3((B_N * A_N + THREADS - 1) / THREADS),
                           dim3(THREADS), 0, stream, locs, scores, anchors, boxes_ws, ms_ws);
        hipLaunchKernelGGL(sort_kernel, dim3(B_N * CF), dim3(THREADS), 0, stream,
                           scores, ms_ws, ranks_ws);
        hipLaunchKernelGGL(chunk_nms_kernel, dim3(B_N * CF), dim3(CTHREADS), 0, stream,
                           scores, ms_ws, boxes_ws, ranks_ws, ws_keys);
    } else if (ws_size >= WS_B_BYTES) {
        hipLaunchKernelGGL(prep_kernel, dim3((B_N * A_N + THREADS - 1) / THREADS),
                           dim3(THREADS), 0, stream, locs, scores, anchors, boxes_ws, ms_ws);
        hipLaunchKernelGGL((nms_mono<true>), dim3(B_N * CF), dim3(THREADS), 0, stream,
                           locs, scores, anchors, boxes_ws, ms_ws, ws_keys);
    } else {
        hipLaunchKernelGGL((nms_mono<false>), dim3(B_N * CF), dim3(THREADS), 0, stream,
                           locs, scores, anchors, boxes_ws, ms_ws, ws_keys);
    }
    hipLaunchKernelGGL(merge_kernel, dim3(B_N), dim3(THREADS), 0, stream,
                       locs, anchors, ws_keys, outp);
}